// Round 14
// baseline (213.907 us; speedup 1.0000x reference)
//
#include <hip/hip_runtime.h>
#include <math.h>

#define B_ 8
#define T_ 4
#define N_ 2048
#define C_ 11
#define D_ 64
#define H_ 4
#define HD_ 16
#define K_ 16
#define BT_ (B_*T_)

__device__ __forceinline__ float softplus_f(float x) {
    return fmaxf(x, 0.f) + log1pf(expf(-fabsf(x)));
}

// ---- Kernel A: block-specialized  [sort (blocks 0..31)] ∥ [embed MLP] -----
__global__ __launch_bounds__(1024) void k_root(
    const float* __restrict__ x,
    const float* __restrict__ w1, const float* __restrict__ b1,
    const float* __restrict__ g1, const float* __restrict__ bb1,
    const float* __restrict__ m1, const float* __restrict__ v1,
    const float* __restrict__ w2, const float* __restrict__ b2,
    const float* __restrict__ g2, const float* __restrict__ bb2,
    const float* __restrict__ m2, const float* __restrict__ v2,
    float* __restrict__ h,
    float2* __restrict__ sp2g, int* __restrict__ sidg, int* __restrict__ fail_cnt)
{
    __shared__ unsigned long long smemU[3072];   // 24 KB, branch-carved
    int t = threadIdx.x;

    if (blockIdx.x < BT_) {
        // ================= sort branch =================
        unsigned long long* kvs = smemU;                 // 2048 ull
        float* lyy = (float*)(smemU + 2048);             // 2048 f
        int bt = blockIdx.x;
        if (t == 0) fail_cnt[bt] = 0;
        const float* xb = x + (size_t)bt * N_ * C_;
        for (int m = t; m < N_; m += 1024) {
            float a = xb[m*C_], b = xb[m*C_+1];
            unsigned int bits = __float_as_uint(a);
            unsigned int u = (bits & 0x80000000u) ? ~bits : (bits | 0x80000000u);
            kvs[m] = ((unsigned long long)u << 11) | (unsigned)m;
            lyy[m] = b;
        }
        __syncthreads();
        for (int k = 2; k <= N_; k <<= 1) {
            for (int j = k >> 1; j > 0; j >>= 1) {
                int p = t;
                int i = ((p & ~(j-1)) << 1) | (p & (j-1));
                int l = i | j;
                unsigned long long a = kvs[i], b = kvs[l];
                bool asc = (i & k) == 0;
                if ((a > b) == asc) { kvs[i] = b; kvs[l] = a; }
                __syncthreads();
            }
        }
        float2* op = sp2g + (size_t)bt * N_;
        int*    oi = sidg + (size_t)bt * N_;
        for (int m = t; m < N_; m += 1024) {
            unsigned long long key = kvs[m];
            int id = (int)(key & 0x7FFull);
            unsigned int u = (unsigned int)(key >> 11);
            unsigned int bits = (u & 0x80000000u) ? (u & 0x7FFFFFFFu) : ~u;
            op[m] = make_float2(__uint_as_float(bits), lyy[id]);
            oi[m] = id;
        }
    } else {
        // ================= embed branch =================
        float* fs  = (float*)smemU;
        float* sw1 = fs;            // 352
        float* sb1 = fs + 352;      // 32
        float* sw2 = fs + 384;      // 2048
        float* sb2 = fs + 2432;     // 64
        if (t < 32) {
            float s = g1[t] / sqrtf(v1[t] + 1e-5f);
            sb1[t] = (b1[t] - m1[t]) * s + bb1[t];
            for (int c = 0; c < C_; ++c) sw1[t*C_+c] = w1[t*C_+c] * s;
        } else if (t >= 64 && t < 128) {
            int j = t - 64;
            float s = g2[j] / sqrtf(v2[j] + 1e-5f);
            sb2[j] = (b2[j] - m2[j]) * s + bb2[j];
            int key = (j >> 4) & 3;
            for (int c = 0; c < 32; ++c)
                sw2[j*32 + ((((c>>2) ^ key) << 2) | (c & 3))] = w2[j*32+c] * s;
        }
        __syncthreads();

        int node = (blockIdx.x - BT_) * 256 + (t >> 2);
        int g = t & 3;
        const float* xp = x + (size_t)node * C_;
        float xin[C_];
        #pragma unroll
        for (int c = 0; c < C_; ++c) xin[c] = xp[c];

        float t1[32];
        #pragma unroll
        for (int j = 0; j < 32; ++j) {
            float a = sb1[j];
            #pragma unroll
            for (int c = 0; c < C_; ++c) a = fmaf(xin[c], sw1[j*C_+c], a);
            t1[j] = fmaxf(a, 0.f);
        }
        float4* hp4 = (float4*)(h + (size_t)node * D_ + g * 16);
        #pragma unroll
        for (int j4 = 0; j4 < 4; ++j4) {
            float o[4];
            #pragma unroll
            for (int u = 0; u < 4; ++u) {
                int j = g*16 + j4*4 + u;
                float a = sb2[j];
                #pragma unroll
                for (int c4 = 0; c4 < 8; ++c4) {
                    float4 w4 = *(const float4*)(&sw2[j*32 + ((c4 ^ g) << 2)]);
                    a = fmaf(t1[4*c4+0], w4.x, a);
                    a = fmaf(t1[4*c4+1], w4.y, a);
                    a = fmaf(t1[4*c4+2], w4.z, a);
                    a = fmaf(t1[4*c4+3], w4.w, a);
                }
                o[u] = fmaxf(a, 0.f);
            }
            hp4[j4] = make_float4(o[0], o[1], o[2], o[3]);
        }
    }
}

// ---- Kernel B: block-specialized [gatw (blocks 0..1023)] ∥ [knn_b1] -------
__global__ __launch_bounds__(256) void k_gatw_b1(
    const float* __restrict__ h, const float* __restrict__ gw,
    const float* __restrict__ att,
    float* __restrict__ hw, float* __restrict__ ssf, float* __restrict__ snbf,
    const float2* __restrict__ sp2g, const int* __restrict__ sidg,
    int* __restrict__ idx, int* __restrict__ fail_cnt, int* __restrict__ fail_lst)
{
    __shared__ float4 smemQ[1088];   // 17408 B, branch-carved
    int t = threadIdx.x;

    if (blockIdx.x < BT_*N_/64) {
        // ================= gatw branch =================
        float* sw   = (float*)smemQ;     // 4096
        float* satA = sw + 4096;         // 128
        for (int i = t; i < D_*D_; i += 256) {
            int r = i >> 6, c = i & 63;
            sw[r*64 + ((((c>>2) ^ ((r>>4)&3)) << 2) | (c & 3))] = gw[i];
        }
        if (t < 2*H_*HD_) satA[t] = att[t];
        __syncthreads();

        int node = blockIdx.x * 64 + (t >> 2);
        int hh = t & 3;
        const float* hp = h + (size_t)node * D_;
        float hin[D_];
        #pragma unroll
        for (int j = 0; j < D_; j += 4) {
            float4 v = *(const float4*)(hp + j);
            hin[j] = v.x; hin[j+1] = v.y; hin[j+2] = v.z; hin[j+3] = v.w;
        }
        float4* wp4 = (float4*)(hw + (size_t)node * D_ + hh * HD_);
        float ss = 0.f, sn = 0.f;
        #pragma unroll
        for (int q4 = 0; q4 < 4; ++q4) {
            float o[4];
            #pragma unroll
            for (int u = 0; u < 4; ++u) {
                const int jj = q4*4 + u;
                const int j = hh*HD_ + jj;
                float a = 0.f;
                #pragma unroll
                for (int c4 = 0; c4 < D_/4; ++c4) {
                    float4 w4 = *(const float4*)(&sw[j*64 + ((c4 ^ hh) << 2)]);
                    a = fmaf(hin[4*c4+0], w4.x, a);
                    a = fmaf(hin[4*c4+1], w4.y, a);
                    a = fmaf(hin[4*c4+2], w4.z, a);
                    a = fmaf(hin[4*c4+3], w4.w, a);
                }
                o[u] = a;
                ss = fmaf(a, satA[hh*(2*HD_) + jj], ss);
                sn = fmaf(a, satA[hh*(2*HD_) + HD_ + jj], sn);
            }
            wp4[q4] = make_float4(o[0], o[1], o[2], o[3]);
        }
        ssf[(size_t)node * H_ + hh] = ss;
        snbf[(size_t)node * H_ + hh] = sn;
        return;
    }

    // ================= knn_b1 branch =================
    float2* spw = (float2*)smemQ;                 // 640 float2
    int* sidw   = (int*)((float*)smemQ + 1280);   // 640
    int* scnt   = sidw + 640;                     // 64
    const int bid   = blockIdx.x - BT_*N_/64;
    const int bt    = bid >> 5;
    const int qbase = (bid & 31) << 6;
    const int base  = qbase - 288;
    const float2* pb = sp2g + (size_t)bt * N_;
    const int*    ib = sidg + (size_t)bt * N_;
    for (int L = t; L < 640; L += 256) {
        int r = base + L;
        if (r < 0 || r >= N_) { spw[L] = make_float2(1e18f, 0.f); sidw[L] = 0; }
        else { spw[L] = pb[r]; sidw[L] = ib[r]; }
    }
    if (t < 64) scnt[t] = 0;
    __syncthreads();

    const int q = t >> 2;
    const int g = t & 3;
    const int s = qbase + q;
    const int sLoc = q + 288;
    const float xs = spw[sLoc].x, ys = spw[sLoc].y;
    const float sqn = __fmaf_rn(xs, xs, __fmul_rn(ys, ys));

    float bd[K_];
    #pragma unroll
    for (int i = 0; i < K_; ++i) bd[i] = 3.402823466e38f;

    for (int i = 0; i < 8; ++i) {
        float d[16];
        #pragma unroll
        for (int j = 0; j < 16; ++j) {
            float2 p = spw[q + 32 + 64*i + 4*j + g];
            float sps = __fmaf_rn(p.x, p.x, __fmul_rn(p.y, p.y));
            float tt = __fmul_rn(xs, p.x);
            tt = __fmaf_rn(ys, p.y, tt);
            d[j] = __fmaf_rn(-2.f, tt, sps);
        }
        // wave-uniform skip: batch can't contribute if its min >= every
        // lane's current 16th value (per-lane conservative -> exactness kept)
        float dmn0 = fminf(fminf(fminf(d[0],d[1]),fminf(d[2],d[3])),
                           fminf(fminf(d[4],d[5]),fminf(d[6],d[7])));
        float dmn1 = fminf(fminf(fminf(d[8],d[9]),fminf(d[10],d[11])),
                           fminf(fminf(d[12],d[13]),fminf(d[14],d[15])));
        if (__all(fminf(dmn0, dmn1) >= bd[K_-1])) continue;
        #pragma unroll
        for (int k = 2; k <= 16; k <<= 1) {
            #pragma unroll
            for (int jj = k >> 1; jj > 0; jj >>= 1) {
                #pragma unroll
                for (int ii = 0; ii < 16; ++ii) {
                    int ll = ii ^ jj;
                    if (ll > ii) {
                        float lo = fminf(d[ii], d[ll]);
                        float hi = fmaxf(d[ii], d[ll]);
                        if ((ii & k) == 0) { d[ii] = lo; d[ll] = hi; }
                        else               { d[ii] = hi; d[ll] = lo; }
                    }
                }
            }
        }
        #pragma unroll
        for (int ii = 0; ii < 16; ++ii) bd[ii] = fminf(bd[ii], d[15-ii]);
        #pragma unroll
        for (int jj = 8; jj > 0; jj >>= 1) {
            #pragma unroll
            for (int ii = 0; ii < 16; ++ii) {
                int ll = ii ^ jj;
                if (ll > ii) {
                    float lo = fminf(bd[ii], bd[ll]);
                    float hi = fmaxf(bd[ii], bd[ll]);
                    bd[ii] = lo; bd[ll] = hi;
                }
            }
        }
    }

    #pragma unroll
    for (int st = 1; st <= 2; st <<= 1) {
        float pr[K_];
        #pragma unroll
        for (int i = 0; i < K_; ++i) pr[i] = __shfl_xor(bd[K_-1-i], st, 64);
        #pragma unroll
        for (int i = 0; i < K_; ++i) bd[i] = fminf(bd[i], pr[i]);
        #pragma unroll
        for (int dd = 8; dd >= 1; dd >>= 1) {
            #pragma unroll
            for (int i = 0; i < K_; ++i) {
                if ((i & dd) == 0) {
                    float lo = fminf(bd[i], bd[i+dd]);
                    float hi = fmaxf(bd[i], bd[i+dd]);
                    bd[i] = lo; bd[i+dd] = hi;
                }
            }
        }
    }
    const float d15 = bd[K_-1];

    float d15s = d15 + sqn;
    float bound = d15s * 1.0001f + (sqn + 1.0f) * 1e-5f;
    bool leftOK = (s - 257 < 0);
    if (!leftOK) { float gp = xs - spw[q+31].x;  leftOK  = (gp*gp >= bound); }
    bool rightOK = (s + 256 > N_-1);
    if (!rightOK){ float gp = spw[q+544].x - xs; rightOK = (gp*gp >= bound); }
    if (!(leftOK && rightOK) && g == 0) {
        int fp = atomicAdd(&fail_cnt[bt], 1);
        fail_lst[bt*N_ + fp] = s;
    }

    int n = sidw[sLoc];
    int* op = idx + ((size_t)bt * N_ + n) * K_;
    for (int i = 0; i < 16; ++i) {
        float d[8];
        int Lb = q + 32 + 32*i + g;
        #pragma unroll
        for (int j = 0; j < 8; ++j) {
            float2 p = spw[Lb + 4*j];
            float sps = __fmaf_rn(p.x, p.x, __fmul_rn(p.y, p.y));
            float tt = __fmul_rn(xs, p.x);
            tt = __fmaf_rn(ys, p.y, tt);
            d[j] = __fmaf_rn(-2.f, tt, sps);
        }
        float dm0 = fminf(fminf(d[0],d[1]), fminf(d[2],d[3]));
        float dm1 = fminf(fminf(d[4],d[5]), fminf(d[6],d[7]));
        if (fminf(dm0, dm1) <= d15) {
            #pragma unroll
            for (int j = 0; j < 8; ++j) {
                if (d[j] <= d15) {
                    int c = atomicAdd(&scnt[q], 1);
                    if (c < K_) op[c] = sidw[Lb + 4*j];
                }
            }
        }
    }
}

// ---- Kernel B2: chunk-parallel full-scan fallback (early-exit grid) -------
__global__ __launch_bounds__(256) void k_knn_b2(const float2* __restrict__ sp2g,
    const int* __restrict__ sidg, const int* __restrict__ fail_cnt,
    const int* __restrict__ fail_lst, int* __restrict__ idx)
{
    const int bt    = blockIdx.x >> 7;
    const int chunk = blockIdx.x & 127;
    const int nf = fail_cnt[bt];
    if (chunk * 16 >= nf) return;

    __shared__ float2 sp[N_];
    __shared__ int sid[N_];
    __shared__ int scnt[16];
    const float2* pb = sp2g + (size_t)bt * N_;
    const int*    ib = sidg + (size_t)bt * N_;
    for (int m = threadIdx.x; m < N_; m += 256) { sp[m] = pb[m]; sid[m] = ib[m]; }
    if (threadIdx.x < 16) scnt[threadIdx.x] = 0;
    __syncthreads();

    const int q = threadIdx.x >> 4;
    const int g = threadIdx.x & 15;
    const bool active = (chunk*16 + q) < nf;
    const int s = active ? fail_lst[bt*N_ + chunk*16 + q] : 0;
    const float xs = sp[s].x, ys = sp[s].y;

    float bd[K_];
    #pragma unroll
    for (int i = 0; i < K_; ++i) bd[i] = 3.402823466e38f;

    for (int i = 0; i < 8; ++i) {
        float d[16];
        #pragma unroll
        for (int j = 0; j < 16; ++j) {
            float2 p = sp[256*i + 16*j + g];
            float sps = __fmaf_rn(p.x, p.x, __fmul_rn(p.y, p.y));
            float tt = __fmul_rn(xs, p.x);
            tt = __fmaf_rn(ys, p.y, tt);
            d[j] = __fmaf_rn(-2.f, tt, sps);
        }
        float dmn0 = fminf(fminf(fminf(d[0],d[1]),fminf(d[2],d[3])),
                           fminf(fminf(d[4],d[5]),fminf(d[6],d[7])));
        float dmn1 = fminf(fminf(fminf(d[8],d[9]),fminf(d[10],d[11])),
                           fminf(fminf(d[12],d[13]),fminf(d[14],d[15])));
        if (__all(fminf(dmn0, dmn1) >= bd[K_-1])) continue;
        #pragma unroll
        for (int k = 2; k <= 16; k <<= 1) {
            #pragma unroll
            for (int jj = k >> 1; jj > 0; jj >>= 1) {
                #pragma unroll
                for (int ii = 0; ii < 16; ++ii) {
                    int ll = ii ^ jj;
                    if (ll > ii) {
                        float lo = fminf(d[ii], d[ll]);
                        float hi = fmaxf(d[ii], d[ll]);
                        if ((ii & k) == 0) { d[ii] = lo; d[ll] = hi; }
                        else               { d[ii] = hi; d[ll] = lo; }
                    }
                }
            }
        }
        #pragma unroll
        for (int ii = 0; ii < 16; ++ii) bd[ii] = fminf(bd[ii], d[15-ii]);
        #pragma unroll
        for (int jj = 8; jj > 0; jj >>= 1) {
            #pragma unroll
            for (int ii = 0; ii < 16; ++ii) {
                int ll = ii ^ jj;
                if (ll > ii) {
                    float lo = fminf(bd[ii], bd[ll]);
                    float hi = fmaxf(bd[ii], bd[ll]);
                    bd[ii] = lo; bd[ll] = hi;
                }
            }
        }
    }

    #pragma unroll
    for (int st = 1; st <= 8; st <<= 1) {
        float pr[K_];
        #pragma unroll
        for (int i = 0; i < K_; ++i) pr[i] = __shfl_xor(bd[K_-1-i], st, 64);
        #pragma unroll
        for (int i = 0; i < K_; ++i) bd[i] = fminf(bd[i], pr[i]);
        #pragma unroll
        for (int dd = 8; dd >= 1; dd >>= 1) {
            #pragma unroll
            for (int i = 0; i < K_; ++i) {
                if ((i & dd) == 0) {
                    float lo = fminf(bd[i], bd[i+dd]);
                    float hi = fmaxf(bd[i], bd[i+dd]);
                    bd[i] = lo; bd[i+dd] = hi;
                }
            }
        }
    }
    const float d15 = bd[K_-1];

    int n = sid[s];
    int* op = idx + ((size_t)bt * N_ + n) * K_;
    for (int i = 0; i < 16; ++i) {
        float d[8];
        #pragma unroll
        for (int j = 0; j < 8; ++j) {
            float2 p = sp[128*i + 16*j + g];
            float sps = __fmaf_rn(p.x, p.x, __fmul_rn(p.y, p.y));
            float tt = __fmul_rn(xs, p.x);
            tt = __fmaf_rn(ys, p.y, tt);
            d[j] = __fmaf_rn(-2.f, tt, sps);
        }
        float dm0 = fminf(fminf(d[0],d[1]), fminf(d[2],d[3]));
        float dm1 = fminf(fminf(d[4],d[5]), fminf(d[6],d[7]));
        if (active && fminf(dm0, dm1) <= d15) {
            #pragma unroll
            for (int j = 0; j < 8; ++j) {
                if (d[j] <= d15) {
                    int c = atomicAdd(&scnt[q], 1);
                    if (c < K_) op[c] = sid[128*i + 16*j + g];
                }
            }
        }
    }
}

// ---- Kernel C2: GAT gather/softmax/aggregate + residual ----
__global__ __launch_bounds__(256, 4) void k_gat(
    const float* __restrict__ hw, const float* __restrict__ ssf,
    const float* __restrict__ snbf,
    const int* __restrict__ idx,
    float* __restrict__ h /* in-out: becomes h_sp */)
{
    const int t = threadIdx.x;
    const int xcd   = blockIdx.x & 7;
    const int local = blockIdx.x >> 3;
    const int btl   = local >> 5;
    const int chunk = local & 31;
    const int bt    = xcd * 4 + btl;
    const int node  = bt * N_ + chunk * 64 + (t >> 2);
    const int hh    = t & 3;

    const int* ip = idx + (size_t)node * K_;
    float ssv = ssf[(size_t)node*H_ + hh];
    const float* hwb = hw + ((size_t)bt * N_) * D_;
    const float* snb = snbf + ((size_t)bt * N_) * H_;

    int nb[K_];
    #pragma unroll
    for (int k = 0; k < K_; ++k) nb[k] = ip[k];

    float sc[K_];
    float mx = -3.402823466e38f;
    #pragma unroll
    for (int k = 0; k < K_; ++k) {
        float s = ssv + snb[(size_t)nb[k]*H_ + hh];
        s = (s >= 0.f) ? s : 0.2f * s;
        sc[k] = s;
        mx = fmaxf(mx, s);
    }
    float den = 0.f;
    #pragma unroll
    for (int k = 0; k < K_; ++k) { sc[k] = __expf(sc[k] - mx); den += sc[k]; }
    float inv = 1.f / den;

    float acc[HD_];
    #pragma unroll
    for (int i = 0; i < HD_; ++i) acc[i] = 0.f;
    #pragma unroll
    for (int k = 0; k < K_; ++k) {
        float al = sc[k] * inv;
        const float* vp = hwb + (size_t)nb[k]*D_ + hh*HD_;
        #pragma unroll
        for (int i = 0; i < HD_; i += 4) {
            float4 v = *(const float4*)(vp + i);
            acc[i]   = fmaf(v.x, al, acc[i]);
            acc[i+1] = fmaf(v.y, al, acc[i+1]);
            acc[i+2] = fmaf(v.z, al, acc[i+2]);
            acc[i+3] = fmaf(v.w, al, acc[i+3]);
        }
    }
    float4* hp4 = (float4*)(h + (size_t)node*D_ + hh*HD_);
    #pragma unroll
    for (int i4 = 0; i4 < 4; ++i4) {
        float4 old = hp4[i4];
        hp4[i4] = make_float4(fmaxf(acc[4*i4+0] + old.x, 0.f),
                              fmaxf(acc[4*i4+1] + old.y, 0.f),
                              fmaxf(acc[4*i4+2] + old.z, 0.f),
                              fmaxf(acc[4*i4+3] + old.w, 0.f));
    }
}

// ---- Kernel D1: Q and KV projections; 4 thr/row; XOR-swizzled weights -----
__global__ __launch_bounds__(256) void k_qkv(
    const float* __restrict__ hsp,
    const float* __restrict__ qw, const float* __restrict__ qb,
    const float* __restrict__ kw, const float* __restrict__ kb,
    float* __restrict__ q, float* __restrict__ kv)
{
    __shared__ float s_qw[D_*D_], s_kw[D_*D_], s_qb[D_], s_kb[D_];
    int t = threadIdx.x;
    for (int i = t; i < D_*D_; i += 256) {
        int r = i >> 6, c = i & 63;
        int p = r*64 + ((((c>>2) ^ ((r>>4)&3)) << 2) | (c & 3));
        s_qw[p] = qw[i]; s_kw[p] = kw[i];
    }
    if (t < D_) { s_qb[t] = qb[t]; s_kb[t] = kb[t]; }
    __syncthreads();

    int r = blockIdx.x * 64 + (t >> 2);
    int g = t & 3;
    const float* in; float* outp; const float* W; const float* bb;
    if (r < BT_*N_) {
        int bt = r >> 11; int n = r & (N_-1);
        int b = bt >> 2, tt = bt & 3;
        in = hsp + (size_t)r * D_;
        outp = kv + (((size_t)(b*N_ + n))*T_ + tt) * D_;
        W = s_kw; bb = s_kb;
    } else {
        int rr = r - BT_*N_;
        int b = rr >> 11, n = rr & (N_-1);
        in = hsp + ((size_t)(b*T_ + (T_-1))*N_ + n) * D_;
        outp = q + (size_t)rr * D_;
        W = s_qw; bb = s_qb;
    }
    float xin[D_];
    #pragma unroll
    for (int j = 0; j < D_; j += 4) {
        float4 v = *(const float4*)(in + j);
        xin[j] = v.x; xin[j+1] = v.y; xin[j+2] = v.z; xin[j+3] = v.w;
    }
    float4* outp4 = (float4*)(outp + g * 16);
    #pragma unroll
    for (int j4 = 0; j4 < 4; ++j4) {
        float o[4];
        #pragma unroll
        for (int u = 0; u < 4; ++u) {
            int j = g*16 + j4*4 + u;
            float a = bb[j];
            #pragma unroll
            for (int c4 = 0; c4 < D_/4; ++c4) {
                float4 w4 = *(const float4*)(&W[j*64 + ((c4 ^ g) << 2)]);
                a = fmaf(xin[4*c4+0], w4.x, a);
                a = fmaf(xin[4*c4+1], w4.y, a);
                a = fmaf(xin[4*c4+2], w4.z, a);
                a = fmaf(xin[4*c4+3], w4.w, a);
            }
            o[u] = a;
        }
        outp4[j4] = make_float4(o[0], o[1], o[2], o[3]);
    }
}

// ---- Kernel D2: temporal attention + output heads ----
__global__ __launch_bounds__(64) void k_head(
    const float* __restrict__ q, const float* __restrict__ kv,
    const float* __restrict__ lw1, const float* __restrict__ lb1,
    const float* __restrict__ lw2, const float* __restrict__ lb2,
    const float* __restrict__ rw1, const float* __restrict__ rb1,
    const float* __restrict__ rw2, const float* __restrict__ rb2,
    float* __restrict__ out)
{
    __shared__ float sl1[32*D_], sr1[32*D_], sl2[4*32], sr2[4*32];
    __shared__ float slb1[32], srb1[32], slb2[4], srb2[4];
    int t = threadIdx.x;
    for (int i = t; i < 32*D_; i += 64) { sl1[i] = lw1[i]; sr1[i] = rw1[i]; }
    for (int i = t; i < 128; i += 64)   { sl2[i] = lw2[i]; sr2[i] = rw2[i]; }
    if (t < 32) { slb1[t] = lb1[t]; srb1[t] = rb1[t]; }
    if (t < 4)  { slb2[t] = lb2[t]; srb2[t] = rb2[t]; }
    __syncthreads();

    int rn = blockIdx.x * 64 + t;
    const float* qp = q + (size_t)rn * D_;
    const float* kp = kv + (size_t)rn * T_ * D_;

    float qv[D_];
    #pragma unroll
    for (int j = 0; j < D_; j += 4) {
        float4 v = *(const float4*)(qp + j);
        qv[j] = v.x; qv[j+1] = v.y; qv[j+2] = v.z; qv[j+3] = v.w;
    }
    float scv[T_];
    #pragma unroll
    for (int tt = 0; tt < T_; ++tt) {
        float a = 0.f;
        const float4* kr = (const float4*)(kp + tt*D_);
        #pragma unroll
        for (int c4 = 0; c4 < D_/4; ++c4) {
            float4 v = kr[c4];
            a = fmaf(qv[4*c4+0], v.x, a);
            a = fmaf(qv[4*c4+1], v.y, a);
            a = fmaf(qv[4*c4+2], v.z, a);
            a = fmaf(qv[4*c4+3], v.w, a);
        }
        scv[tt] = a * 0.125f;
    }
    float mx = fmaxf(fmaxf(scv[0], scv[1]), fmaxf(scv[2], scv[3]));
    float wsum = 0.f;
    #pragma unroll
    for (int tt = 0; tt < T_; ++tt) { scv[tt] = expf(scv[tt] - mx); wsum += scv[tt]; }
    float winv = 1.f / wsum;

    float hf[D_];
    #pragma unroll
    for (int j = 0; j < D_; ++j) hf[j] = 0.f;
    #pragma unroll
    for (int tt = 0; tt < T_; ++tt) {
        float w = scv[tt] * winv;
        const float4* kr = (const float4*)(kp + tt*D_);
        #pragma unroll
        for (int c4 = 0; c4 < D_/4; ++c4) {
            float4 v = kr[c4];
            hf[4*c4+0] = fmaf(v.x, w, hf[4*c4+0]);
            hf[4*c4+1] = fmaf(v.y, w, hf[4*c4+1]);
            hf[4*c4+2] = fmaf(v.z, w, hf[4*c4+2]);
            hf[4*c4+3] = fmaf(v.w, w, hf[4*c4+3]);
        }
    }
    float ol0 = slb2[0], ol1 = slb2[1], ol2 = slb2[2], ol3 = slb2[3];
    #pragma unroll 2
    for (int j = 0; j < 32; ++j) {
        float a = slb1[j];
        const float4* wr = (const float4*)(&sl1[j*D_]);
        #pragma unroll
        for (int c4 = 0; c4 < D_/4; ++c4) {
            float4 v = wr[c4];
            a = fmaf(hf[4*c4+0], v.x, a);
            a = fmaf(hf[4*c4+1], v.y, a);
            a = fmaf(hf[4*c4+2], v.z, a);
            a = fmaf(hf[4*c4+3], v.w, a);
        }
        a = fmaxf(a, 0.f);
        ol0 = fmaf(a, sl2[0*32+j], ol0);
        ol1 = fmaf(a, sl2[1*32+j], ol1);
        ol2 = fmaf(a, sl2[2*32+j], ol2);
        ol3 = fmaf(a, sl2[3*32+j], ol3);
    }
    float or0 = srb2[0], or1 = srb2[1], or2 = srb2[2], or3 = srb2[3];
    #pragma unroll 2
    for (int j = 0; j < 32; ++j) {
        float a = srb1[j];
        const float4* wr = (const float4*)(&sr1[j*D_]);
        #pragma unroll
        for (int c4 = 0; c4 < D_/4; ++c4) {
            float4 v = wr[c4];
            a = fmaf(hf[4*c4+0], v.x, a);
            a = fmaf(hf[4*c4+1], v.y, a);
            a = fmaf(hf[4*c4+2], v.z, a);
            a = fmaf(hf[4*c4+3], v.w, a);
        }
        a = fmaxf(a, 0.f);
        or0 = fmaf(a, sr2[0*32+j], or0);
        or1 = fmaf(a, sr2[1*32+j], or1);
        or2 = fmaf(a, sr2[2*32+j], or2);
        or3 = fmaf(a, sr2[3*32+j], or3);
    }
    const int NB = B_ * N_;
    out[0*2*NB + rn*2 + 0] = ol0;
    out[0*2*NB + rn*2 + 1] = ol1;
    out[1*2*NB + rn*2 + 0] = softplus_f(ol2) + 1e-6f;
    out[1*2*NB + rn*2 + 1] = softplus_f(ol3) + 1e-6f;
    out[2*2*NB + rn*2 + 0] = or0;
    out[2*2*NB + rn*2 + 1] = or1;
    out[3*2*NB + rn*2 + 0] = softplus_f(or2) + 1e-6f;
    out[3*2*NB + rn*2 + 1] = softplus_f(or3) + 1e-6f;
}

// ---- launcher ----
extern "C" void kernel_launch(void* const* d_in, const int* in_sizes, int n_in,
                              void* d_out, int out_size, void* d_ws, size_t ws_size,
                              hipStream_t stream)
{
    const float* x   = (const float*)d_in[0];
    const float* ew1 = (const float*)d_in[1];
    const float* eb1 = (const float*)d_in[2];
    const float* g1  = (const float*)d_in[3];
    const float* bb1 = (const float*)d_in[4];
    const float* m1  = (const float*)d_in[5];
    const float* v1  = (const float*)d_in[6];
    const float* ew2 = (const float*)d_in[7];
    const float* eb2 = (const float*)d_in[8];
    const float* g2  = (const float*)d_in[9];
    const float* bb2 = (const float*)d_in[10];
    const float* m2  = (const float*)d_in[11];
    const float* v2  = (const float*)d_in[12];
    const float* gw  = (const float*)d_in[13];
    const float* att = (const float*)d_in[14];
    const float* qw  = (const float*)d_in[15];
    const float* qb  = (const float*)d_in[16];
    const float* kw  = (const float*)d_in[17];
    const float* kb  = (const float*)d_in[18];
    const float* lw1 = (const float*)d_in[19];
    const float* lb1 = (const float*)d_in[20];
    const float* lw2 = (const float*)d_in[21];
    const float* lb2 = (const float*)d_in[22];
    const float* rw1 = (const float*)d_in[23];
    const float* rb1 = (const float*)d_in[24];
    const float* rw2 = (const float*)d_in[25];
    const float* rb2 = (const float*)d_in[26];
    float* out = (float*)d_out;

    const size_t NTOT = (size_t)BT_*N_;                 // 65536
    float* h    = (float*)d_ws;                         // NTOT*64
    float* hw   = h   + NTOT*D_;                        // NTOT*64
    float* kvb  = hw  + NTOT*D_;                        // NTOT*64
    float* ssf  = kvb + NTOT*D_;                        // NTOT*4
    float* snbf = ssf + NTOT*H_;                        // NTOT*4
    int*   idx  = (int*)(snbf + NTOT*H_);               // NTOT*16
    float* q    = (float*)(idx + NTOT*K_);              // B*N*64
    float2* sp2g = (float2*)(q + (size_t)B_*N_*D_);     // NTOT float2
    int*   sidg = (int*)((float*)sp2g + 2*NTOT);        // NTOT
    int*   fail_cnt = sidg + NTOT;                      // 32
    int*   fail_lst = fail_cnt + 32;                    // NTOT

    k_root<<<BT_ + BT_*N_/256, 1024, 0, stream>>>(x, ew1, eb1, g1, bb1, m1, v1,
                                                  ew2, eb2, g2, bb2, m2, v2,
                                                  h, sp2g, sidg, fail_cnt);
    k_gatw_b1<<<BT_*N_/64 + BT_*(N_/64), 256, 0, stream>>>(
        h, gw, att, hw, ssf, snbf, sp2g, sidg, idx, fail_cnt, fail_lst);
    k_knn_b2<<<BT_*128, 256, 0, stream>>>(sp2g, sidg, fail_cnt, fail_lst, idx);
    k_gat<<<(BT_*N_*H_)/256, 256, 0, stream>>>(hw, ssf, snbf, idx, h);
    k_qkv<<<(BT_*N_ + B_*N_)/64, 256, 0, stream>>>(h, qw, qb, kw, kb, q, kvb);
    k_head<<<(B_*N_)/64, 64, 0, stream>>>(q, kvb, lw1, lb1, lw2, lb2,
                                          rw1, rb1, rw2, rb2, out);
}

// Round 15
// 213.744 us; speedup vs baseline: 1.0008x; 1.0008x over previous
//
#include <hip/hip_runtime.h>
#include <math.h>

#define B_ 8
#define T_ 4
#define N_ 2048
#define C_ 11
#define D_ 64
#define H_ 4
#define HD_ 16
#define K_ 16
#define BT_ (B_*T_)

__device__ __forceinline__ float softplus_f(float x) {
    return fmaxf(x, 0.f) + log1pf(expf(-fabsf(x)));
}

// ---- Kernel A: block-specialized  [sort (blocks 0..31)] ∥ [embed MLP] -----
__global__ __launch_bounds__(1024) void k_root(
    const float* __restrict__ x,
    const float* __restrict__ w1, const float* __restrict__ b1,
    const float* __restrict__ g1, const float* __restrict__ bb1,
    const float* __restrict__ m1, const float* __restrict__ v1,
    const float* __restrict__ w2, const float* __restrict__ b2,
    const float* __restrict__ g2, const float* __restrict__ bb2,
    const float* __restrict__ m2, const float* __restrict__ v2,
    float* __restrict__ h,
    float2* __restrict__ sp2g, int* __restrict__ sidg, int* __restrict__ fail_cnt)
{
    __shared__ unsigned long long smemU[3072];   // 24 KB, branch-carved
    int t = threadIdx.x;

    if (blockIdx.x < BT_) {
        // ================= sort branch =================
        unsigned long long* kvs = smemU;                 // 2048 ull
        float* lyy = (float*)(smemU + 2048);             // 2048 f
        int bt = blockIdx.x;
        if (t == 0) fail_cnt[bt] = 0;
        const float* xb = x + (size_t)bt * N_ * C_;
        for (int m = t; m < N_; m += 1024) {
            float a = xb[m*C_], b = xb[m*C_+1];
            unsigned int bits = __float_as_uint(a);
            unsigned int u = (bits & 0x80000000u) ? ~bits : (bits | 0x80000000u);
            kvs[m] = ((unsigned long long)u << 11) | (unsigned)m;
            lyy[m] = b;
        }
        __syncthreads();
        for (int k = 2; k <= N_; k <<= 1) {
            for (int j = k >> 1; j > 0; j >>= 1) {
                int p = t;
                int i = ((p & ~(j-1)) << 1) | (p & (j-1));
                int l = i | j;
                unsigned long long a = kvs[i], b = kvs[l];
                bool asc = (i & k) == 0;
                if ((a > b) == asc) { kvs[i] = b; kvs[l] = a; }
                __syncthreads();
            }
        }
        float2* op = sp2g + (size_t)bt * N_;
        int*    oi = sidg + (size_t)bt * N_;
        for (int m = t; m < N_; m += 1024) {
            unsigned long long key = kvs[m];
            int id = (int)(key & 0x7FFull);
            unsigned int u = (unsigned int)(key >> 11);
            unsigned int bits = (u & 0x80000000u) ? (u & 0x7FFFFFFFu) : ~u;
            op[m] = make_float2(__uint_as_float(bits), lyy[id]);
            oi[m] = id;
        }
    } else {
        // ================= embed branch =================
        float* fs  = (float*)smemU;
        float* sw1 = fs;            // 352
        float* sb1 = fs + 352;      // 32
        float* sw2 = fs + 384;      // 2048
        float* sb2 = fs + 2432;     // 64
        if (t < 32) {
            float s = g1[t] / sqrtf(v1[t] + 1e-5f);
            sb1[t] = (b1[t] - m1[t]) * s + bb1[t];
            for (int c = 0; c < C_; ++c) sw1[t*C_+c] = w1[t*C_+c] * s;
        } else if (t >= 64 && t < 128) {
            int j = t - 64;
            float s = g2[j] / sqrtf(v2[j] + 1e-5f);
            sb2[j] = (b2[j] - m2[j]) * s + bb2[j];
            int key = (j >> 4) & 3;
            for (int c = 0; c < 32; ++c)
                sw2[j*32 + ((((c>>2) ^ key) << 2) | (c & 3))] = w2[j*32+c] * s;
        }
        __syncthreads();

        int node = (blockIdx.x - BT_) * 256 + (t >> 2);
        int g = t & 3;
        const float* xp = x + (size_t)node * C_;
        float xin[C_];
        #pragma unroll
        for (int c = 0; c < C_; ++c) xin[c] = xp[c];

        float t1[32];
        #pragma unroll
        for (int j = 0; j < 32; ++j) {
            float a = sb1[j];
            #pragma unroll
            for (int c = 0; c < C_; ++c) a = fmaf(xin[c], sw1[j*C_+c], a);
            t1[j] = fmaxf(a, 0.f);
        }
        float4* hp4 = (float4*)(h + (size_t)node * D_ + g * 16);
        #pragma unroll
        for (int j4 = 0; j4 < 4; ++j4) {
            float o[4];
            #pragma unroll
            for (int u = 0; u < 4; ++u) {
                int j = g*16 + j4*4 + u;
                float a = sb2[j];
                #pragma unroll
                for (int c4 = 0; c4 < 8; ++c4) {
                    float4 w4 = *(const float4*)(&sw2[j*32 + ((c4 ^ g) << 2)]);
                    a = fmaf(t1[4*c4+0], w4.x, a);
                    a = fmaf(t1[4*c4+1], w4.y, a);
                    a = fmaf(t1[4*c4+2], w4.z, a);
                    a = fmaf(t1[4*c4+3], w4.w, a);
                }
                o[u] = fmaxf(a, 0.f);
            }
            hp4[j4] = make_float4(o[0], o[1], o[2], o[3]);
        }
    }
}

// ---- Kernel B: block-specialized [gatw (blocks 0..1023)] ∥ [knn_b1] -------
__global__ __launch_bounds__(256) void k_gatw_b1(
    const float* __restrict__ h, const float* __restrict__ gw,
    const float* __restrict__ att,
    float* __restrict__ hw, float* __restrict__ ssf, float* __restrict__ snbf,
    const float2* __restrict__ sp2g, const int* __restrict__ sidg,
    int* __restrict__ idx, int* __restrict__ fail_cnt, int* __restrict__ fail_lst)
{
    __shared__ float4 smemQ[1088];   // 17408 B, branch-carved
    int t = threadIdx.x;

    if (blockIdx.x < BT_*N_/64) {
        // ================= gatw branch =================
        float* sw   = (float*)smemQ;     // 4096
        float* satA = sw + 4096;         // 128
        for (int i = t; i < D_*D_; i += 256) {
            int r = i >> 6, c = i & 63;
            sw[r*64 + ((((c>>2) ^ ((r>>4)&3)) << 2) | (c & 3))] = gw[i];
        }
        if (t < 2*H_*HD_) satA[t] = att[t];
        __syncthreads();

        int node = blockIdx.x * 64 + (t >> 2);
        int hh = t & 3;
        const float* hp = h + (size_t)node * D_;
        float hin[D_];
        #pragma unroll
        for (int j = 0; j < D_; j += 4) {
            float4 v = *(const float4*)(hp + j);
            hin[j] = v.x; hin[j+1] = v.y; hin[j+2] = v.z; hin[j+3] = v.w;
        }
        float4* wp4 = (float4*)(hw + (size_t)node * D_ + hh * HD_);
        float ss = 0.f, sn = 0.f;
        #pragma unroll
        for (int q4 = 0; q4 < 4; ++q4) {
            float o[4];
            #pragma unroll
            for (int u = 0; u < 4; ++u) {
                const int jj = q4*4 + u;
                const int j = hh*HD_ + jj;
                float a = 0.f;
                #pragma unroll
                for (int c4 = 0; c4 < D_/4; ++c4) {
                    float4 w4 = *(const float4*)(&sw[j*64 + ((c4 ^ hh) << 2)]);
                    a = fmaf(hin[4*c4+0], w4.x, a);
                    a = fmaf(hin[4*c4+1], w4.y, a);
                    a = fmaf(hin[4*c4+2], w4.z, a);
                    a = fmaf(hin[4*c4+3], w4.w, a);
                }
                o[u] = a;
                ss = fmaf(a, satA[hh*(2*HD_) + jj], ss);
                sn = fmaf(a, satA[hh*(2*HD_) + HD_ + jj], sn);
            }
            wp4[q4] = make_float4(o[0], o[1], o[2], o[3]);
        }
        ssf[(size_t)node * H_ + hh] = ss;
        snbf[(size_t)node * H_ + hh] = sn;
        return;
    }

    // ================= knn_b1 branch =================
    float2* spw = (float2*)smemQ;                 // 640 float2
    int* sidw   = (int*)((float*)smemQ + 1280);   // 640
    int* scnt   = sidw + 640;                     // 64
    const int bid   = blockIdx.x - BT_*N_/64;
    const int bt    = bid >> 5;
    const int qbase = (bid & 31) << 6;
    const int base  = qbase - 288;
    const float2* pb = sp2g + (size_t)bt * N_;
    const int*    ib = sidg + (size_t)bt * N_;
    for (int L = t; L < 640; L += 256) {
        int r = base + L;
        if (r < 0 || r >= N_) { spw[L] = make_float2(1e18f, 0.f); sidw[L] = 0; }
        else { spw[L] = pb[r]; sidw[L] = ib[r]; }
    }
    if (t < 64) scnt[t] = 0;
    __syncthreads();

    const int q = t >> 2;
    const int g = t & 3;
    const int s = qbase + q;
    const int sLoc = q + 288;
    const float xs = spw[sLoc].x, ys = spw[sLoc].y;
    const float sqn = __fmaf_rn(xs, xs, __fmul_rn(ys, ys));

    float bd[K_];
    #pragma unroll
    for (int i = 0; i < K_; ++i) bd[i] = 3.402823466e38f;

    // center-outward batch order: query sits in batch 4 of the window, so
    // process nearest-rank batches first -> bd[15] tightens immediately and
    // the far batches hit the wave-uniform skip.
    const int ord[8] = {4, 3, 5, 2, 6, 1, 7, 0};
    #pragma unroll
    for (int io = 0; io < 8; ++io) {
        const int i = ord[io];
        float d[16];
        #pragma unroll
        for (int j = 0; j < 16; ++j) {
            float2 p = spw[q + 32 + 64*i + 4*j + g];
            float sps = __fmaf_rn(p.x, p.x, __fmul_rn(p.y, p.y));
            float tt = __fmul_rn(xs, p.x);
            tt = __fmaf_rn(ys, p.y, tt);
            d[j] = __fmaf_rn(-2.f, tt, sps);
        }
        // wave-uniform skip (per-lane conservative -> exactness kept)
        float dmn0 = fminf(fminf(fminf(d[0],d[1]),fminf(d[2],d[3])),
                           fminf(fminf(d[4],d[5]),fminf(d[6],d[7])));
        float dmn1 = fminf(fminf(fminf(d[8],d[9]),fminf(d[10],d[11])),
                           fminf(fminf(d[12],d[13]),fminf(d[14],d[15])));
        if (__all(fminf(dmn0, dmn1) >= bd[K_-1])) continue;
        #pragma unroll
        for (int k = 2; k <= 16; k <<= 1) {
            #pragma unroll
            for (int jj = k >> 1; jj > 0; jj >>= 1) {
                #pragma unroll
                for (int ii = 0; ii < 16; ++ii) {
                    int ll = ii ^ jj;
                    if (ll > ii) {
                        float lo = fminf(d[ii], d[ll]);
                        float hi = fmaxf(d[ii], d[ll]);
                        if ((ii & k) == 0) { d[ii] = lo; d[ll] = hi; }
                        else               { d[ii] = hi; d[ll] = lo; }
                    }
                }
            }
        }
        #pragma unroll
        for (int ii = 0; ii < 16; ++ii) bd[ii] = fminf(bd[ii], d[15-ii]);
        #pragma unroll
        for (int jj = 8; jj > 0; jj >>= 1) {
            #pragma unroll
            for (int ii = 0; ii < 16; ++ii) {
                int ll = ii ^ jj;
                if (ll > ii) {
                    float lo = fminf(bd[ii], bd[ll]);
                    float hi = fmaxf(bd[ii], bd[ll]);
                    bd[ii] = lo; bd[ll] = hi;
                }
            }
        }
    }

    #pragma unroll
    for (int st = 1; st <= 2; st <<= 1) {
        float pr[K_];
        #pragma unroll
        for (int i = 0; i < K_; ++i) pr[i] = __shfl_xor(bd[K_-1-i], st, 64);
        #pragma unroll
        for (int i = 0; i < K_; ++i) bd[i] = fminf(bd[i], pr[i]);
        #pragma unroll
        for (int dd = 8; dd >= 1; dd >>= 1) {
            #pragma unroll
            for (int i = 0; i < K_; ++i) {
                if ((i & dd) == 0) {
                    float lo = fminf(bd[i], bd[i+dd]);
                    float hi = fmaxf(bd[i], bd[i+dd]);
                    bd[i] = lo; bd[i+dd] = hi;
                }
            }
        }
    }
    const float d15 = bd[K_-1];

    float d15s = d15 + sqn;
    float bound = d15s * 1.0001f + (sqn + 1.0f) * 1e-5f;
    bool leftOK = (s - 257 < 0);
    if (!leftOK) { float gp = xs - spw[q+31].x;  leftOK  = (gp*gp >= bound); }
    bool rightOK = (s + 256 > N_-1);
    if (!rightOK){ float gp = spw[q+544].x - xs; rightOK = (gp*gp >= bound); }
    if (!(leftOK && rightOK) && g == 0) {
        int fp = atomicAdd(&fail_cnt[bt], 1);
        fail_lst[bt*N_ + fp] = s;
    }

    int n = sidw[sLoc];
    int* op = idx + ((size_t)bt * N_ + n) * K_;
    for (int i = 0; i < 16; ++i) {
        float d[8];
        int Lb = q + 32 + 32*i + g;
        #pragma unroll
        for (int j = 0; j < 8; ++j) {
            float2 p = spw[Lb + 4*j];
            float sps = __fmaf_rn(p.x, p.x, __fmul_rn(p.y, p.y));
            float tt = __fmul_rn(xs, p.x);
            tt = __fmaf_rn(ys, p.y, tt);
            d[j] = __fmaf_rn(-2.f, tt, sps);
        }
        float dm0 = fminf(fminf(d[0],d[1]), fminf(d[2],d[3]));
        float dm1 = fminf(fminf(d[4],d[5]), fminf(d[6],d[7]));
        if (fminf(dm0, dm1) <= d15) {
            #pragma unroll
            for (int j = 0; j < 8; ++j) {
                if (d[j] <= d15) {
                    int c = atomicAdd(&scnt[q], 1);
                    if (c < K_) op[c] = sidw[Lb + 4*j];
                }
            }
        }
    }
}

// ---- Kernel B2: chunk-parallel full-scan fallback (early-exit grid) -------
__global__ __launch_bounds__(256) void k_knn_b2(const float2* __restrict__ sp2g,
    const int* __restrict__ sidg, const int* __restrict__ fail_cnt,
    const int* __restrict__ fail_lst, int* __restrict__ idx)
{
    const int bt    = blockIdx.x >> 7;
    const int chunk = blockIdx.x & 127;
    const int nf = fail_cnt[bt];
    if (chunk * 16 >= nf) return;

    __shared__ float2 sp[N_];
    __shared__ int sid[N_];
    __shared__ int scnt[16];
    const float2* pb = sp2g + (size_t)bt * N_;
    const int*    ib = sidg + (size_t)bt * N_;
    for (int m = threadIdx.x; m < N_; m += 256) { sp[m] = pb[m]; sid[m] = ib[m]; }
    if (threadIdx.x < 16) scnt[threadIdx.x] = 0;
    __syncthreads();

    const int q = threadIdx.x >> 4;
    const int g = threadIdx.x & 15;
    const bool active = (chunk*16 + q) < nf;
    const int s = active ? fail_lst[bt*N_ + chunk*16 + q] : 0;
    const float xs = sp[s].x, ys = sp[s].y;

    float bd[K_];
    #pragma unroll
    for (int i = 0; i < K_; ++i) bd[i] = 3.402823466e38f;

    for (int i = 0; i < 8; ++i) {
        float d[16];
        #pragma unroll
        for (int j = 0; j < 16; ++j) {
            float2 p = sp[256*i + 16*j + g];
            float sps = __fmaf_rn(p.x, p.x, __fmul_rn(p.y, p.y));
            float tt = __fmul_rn(xs, p.x);
            tt = __fmaf_rn(ys, p.y, tt);
            d[j] = __fmaf_rn(-2.f, tt, sps);
        }
        float dmn0 = fminf(fminf(fminf(d[0],d[1]),fminf(d[2],d[3])),
                           fminf(fminf(d[4],d[5]),fminf(d[6],d[7])));
        float dmn1 = fminf(fminf(fminf(d[8],d[9]),fminf(d[10],d[11])),
                           fminf(fminf(d[12],d[13]),fminf(d[14],d[15])));
        if (__all(fminf(dmn0, dmn1) >= bd[K_-1])) continue;
        #pragma unroll
        for (int k = 2; k <= 16; k <<= 1) {
            #pragma unroll
            for (int jj = k >> 1; jj > 0; jj >>= 1) {
                #pragma unroll
                for (int ii = 0; ii < 16; ++ii) {
                    int ll = ii ^ jj;
                    if (ll > ii) {
                        float lo = fminf(d[ii], d[ll]);
                        float hi = fmaxf(d[ii], d[ll]);
                        if ((ii & k) == 0) { d[ii] = lo; d[ll] = hi; }
                        else               { d[ii] = hi; d[ll] = lo; }
                    }
                }
            }
        }
        #pragma unroll
        for (int ii = 0; ii < 16; ++ii) bd[ii] = fminf(bd[ii], d[15-ii]);
        #pragma unroll
        for (int jj = 8; jj > 0; jj >>= 1) {
            #pragma unroll
            for (int ii = 0; ii < 16; ++ii) {
                int ll = ii ^ jj;
                if (ll > ii) {
                    float lo = fminf(bd[ii], bd[ll]);
                    float hi = fmaxf(bd[ii], bd[ll]);
                    bd[ii] = lo; bd[ll] = hi;
                }
            }
        }
    }

    #pragma unroll
    for (int st = 1; st <= 8; st <<= 1) {
        float pr[K_];
        #pragma unroll
        for (int i = 0; i < K_; ++i) pr[i] = __shfl_xor(bd[K_-1-i], st, 64);
        #pragma unroll
        for (int i = 0; i < K_; ++i) bd[i] = fminf(bd[i], pr[i]);
        #pragma unroll
        for (int dd = 8; dd >= 1; dd >>= 1) {
            #pragma unroll
            for (int i = 0; i < K_; ++i) {
                if ((i & dd) == 0) {
                    float lo = fminf(bd[i], bd[i+dd]);
                    float hi = fmaxf(bd[i], bd[i+dd]);
                    bd[i] = lo; bd[i+dd] = hi;
                }
            }
        }
    }
    const float d15 = bd[K_-1];

    int n = sid[s];
    int* op = idx + ((size_t)bt * N_ + n) * K_;
    for (int i = 0; i < 16; ++i) {
        float d[8];
        #pragma unroll
        for (int j = 0; j < 8; ++j) {
            float2 p = sp[128*i + 16*j + g];
            float sps = __fmaf_rn(p.x, p.x, __fmul_rn(p.y, p.y));
            float tt = __fmul_rn(xs, p.x);
            tt = __fmaf_rn(ys, p.y, tt);
            d[j] = __fmaf_rn(-2.f, tt, sps);
        }
        float dm0 = fminf(fminf(d[0],d[1]), fminf(d[2],d[3]));
        float dm1 = fminf(fminf(d[4],d[5]), fminf(d[6],d[7]));
        if (active && fminf(dm0, dm1) <= d15) {
            #pragma unroll
            for (int j = 0; j < 8; ++j) {
                if (d[j] <= d15) {
                    int c = atomicAdd(&scnt[q], 1);
                    if (c < K_) op[c] = sid[128*i + 16*j + g];
                }
            }
        }
    }
}

// ---- Kernel C2: GAT gather/softmax/aggregate + residual ----
__global__ __launch_bounds__(256, 4) void k_gat(
    const float* __restrict__ hw, const float* __restrict__ ssf,
    const float* __restrict__ snbf,
    const int* __restrict__ idx,
    float* __restrict__ h /* in-out: becomes h_sp */)
{
    const int t = threadIdx.x;
    const int xcd   = blockIdx.x & 7;
    const int local = blockIdx.x >> 3;
    const int btl   = local >> 5;
    const int chunk = local & 31;
    const int bt    = xcd * 4 + btl;
    const int node  = bt * N_ + chunk * 64 + (t >> 2);
    const int hh    = t & 3;

    const int* ip = idx + (size_t)node * K_;
    float ssv = ssf[(size_t)node*H_ + hh];
    const float* hwb = hw + ((size_t)bt * N_) * D_;
    const float* snb = snbf + ((size_t)bt * N_) * H_;

    int nb[K_];
    #pragma unroll
    for (int k = 0; k < K_; ++k) nb[k] = ip[k];

    float sc[K_];
    float mx = -3.402823466e38f;
    #pragma unroll
    for (int k = 0; k < K_; ++k) {
        float s = ssv + snb[(size_t)nb[k]*H_ + hh];
        s = (s >= 0.f) ? s : 0.2f * s;
        sc[k] = s;
        mx = fmaxf(mx, s);
    }
    float den = 0.f;
    #pragma unroll
    for (int k = 0; k < K_; ++k) { sc[k] = __expf(sc[k] - mx); den += sc[k]; }
    float inv = 1.f / den;

    float acc[HD_];
    #pragma unroll
    for (int i = 0; i < HD_; ++i) acc[i] = 0.f;
    #pragma unroll
    for (int k = 0; k < K_; ++k) {
        float al = sc[k] * inv;
        const float* vp = hwb + (size_t)nb[k]*D_ + hh*HD_;
        #pragma unroll
        for (int i = 0; i < HD_; i += 4) {
            float4 v = *(const float4*)(vp + i);
            acc[i]   = fmaf(v.x, al, acc[i]);
            acc[i+1] = fmaf(v.y, al, acc[i+1]);
            acc[i+2] = fmaf(v.z, al, acc[i+2]);
            acc[i+3] = fmaf(v.w, al, acc[i+3]);
        }
    }
    float4* hp4 = (float4*)(h + (size_t)node*D_ + hh*HD_);
    #pragma unroll
    for (int i4 = 0; i4 < 4; ++i4) {
        float4 old = hp4[i4];
        hp4[i4] = make_float4(fmaxf(acc[4*i4+0] + old.x, 0.f),
                              fmaxf(acc[4*i4+1] + old.y, 0.f),
                              fmaxf(acc[4*i4+2] + old.z, 0.f),
                              fmaxf(acc[4*i4+3] + old.w, 0.f));
    }
}

// ---- Kernel D1: Q and KV projections; 4 thr/row; XOR-swizzled weights -----
__global__ __launch_bounds__(256) void k_qkv(
    const float* __restrict__ hsp,
    const float* __restrict__ qw, const float* __restrict__ qb,
    const float* __restrict__ kw, const float* __restrict__ kb,
    float* __restrict__ q, float* __restrict__ kv)
{
    __shared__ float s_qw[D_*D_], s_kw[D_*D_], s_qb[D_], s_kb[D_];
    int t = threadIdx.x;
    for (int i = t; i < D_*D_; i += 256) {
        int r = i >> 6, c = i & 63;
        int p = r*64 + ((((c>>2) ^ ((r>>4)&3)) << 2) | (c & 3));
        s_qw[p] = qw[i]; s_kw[p] = kw[i];
    }
    if (t < D_) { s_qb[t] = qb[t]; s_kb[t] = kb[t]; }
    __syncthreads();

    int r = blockIdx.x * 64 + (t >> 2);
    int g = t & 3;
    const float* in; float* outp; const float* W; const float* bb;
    if (r < BT_*N_) {
        int bt = r >> 11; int n = r & (N_-1);
        int b = bt >> 2, tt = bt & 3;
        in = hsp + (size_t)r * D_;
        outp = kv + (((size_t)(b*N_ + n))*T_ + tt) * D_;
        W = s_kw; bb = s_kb;
    } else {
        int rr = r - BT_*N_;
        int b = rr >> 11, n = rr & (N_-1);
        in = hsp + ((size_t)(b*T_ + (T_-1))*N_ + n) * D_;
        outp = q + (size_t)rr * D_;
        W = s_qw; bb = s_qb;
    }
    float xin[D_];
    #pragma unroll
    for (int j = 0; j < D_; j += 4) {
        float4 v = *(const float4*)(in + j);
        xin[j] = v.x; xin[j+1] = v.y; xin[j+2] = v.z; xin[j+3] = v.w;
    }
    float4* outp4 = (float4*)(outp + g * 16);
    #pragma unroll
    for (int j4 = 0; j4 < 4; ++j4) {
        float o[4];
        #pragma unroll
        for (int u = 0; u < 4; ++u) {
            int j = g*16 + j4*4 + u;
            float a = bb[j];
            #pragma unroll
            for (int c4 = 0; c4 < D_/4; ++c4) {
                float4 w4 = *(const float4*)(&W[j*64 + ((c4 ^ g) << 2)]);
                a = fmaf(xin[4*c4+0], w4.x, a);
                a = fmaf(xin[4*c4+1], w4.y, a);
                a = fmaf(xin[4*c4+2], w4.z, a);
                a = fmaf(xin[4*c4+3], w4.w, a);
            }
            o[u] = a;
        }
        outp4[j4] = make_float4(o[0], o[1], o[2], o[3]);
    }
}

// ---- Kernel D2: temporal attention + output heads ----
__global__ __launch_bounds__(64) void k_head(
    const float* __restrict__ q, const float* __restrict__ kv,
    const float* __restrict__ lw1, const float* __restrict__ lb1,
    const float* __restrict__ lw2, const float* __restrict__ lb2,
    const float* __restrict__ rw1, const float* __restrict__ rb1,
    const float* __restrict__ rw2, const float* __restrict__ rb2,
    float* __restrict__ out)
{
    __shared__ float sl1[32*D_], sr1[32*D_], sl2[4*32], sr2[4*32];
    __shared__ float slb1[32], srb1[32], slb2[4], srb2[4];
    int t = threadIdx.x;
    for (int i = t; i < 32*D_; i += 64) { sl1[i] = lw1[i]; sr1[i] = rw1[i]; }
    for (int i = t; i < 128; i += 64)   { sl2[i] = lw2[i]; sr2[i] = rw2[i]; }
    if (t < 32) { slb1[t] = lb1[t]; srb1[t] = rb1[t]; }
    if (t < 4)  { slb2[t] = lb2[t]; srb2[t] = rb2[t]; }
    __syncthreads();

    int rn = blockIdx.x * 64 + t;
    const float* qp = q + (size_t)rn * D_;
    const float* kp = kv + (size_t)rn * T_ * D_;

    float qv[D_];
    #pragma unroll
    for (int j = 0; j < D_; j += 4) {
        float4 v = *(const float4*)(qp + j);
        qv[j] = v.x; qv[j+1] = v.y; qv[j+2] = v.z; qv[j+3] = v.w;
    }
    float scv[T_];
    #pragma unroll
    for (int tt = 0; tt < T_; ++tt) {
        float a = 0.f;
        const float4* kr = (const float4*)(kp + tt*D_);
        #pragma unroll
        for (int c4 = 0; c4 < D_/4; ++c4) {
            float4 v = kr[c4];
            a = fmaf(qv[4*c4+0], v.x, a);
            a = fmaf(qv[4*c4+1], v.y, a);
            a = fmaf(qv[4*c4+2], v.z, a);
            a = fmaf(qv[4*c4+3], v.w, a);
        }
        scv[tt] = a * 0.125f;
    }
    float mx = fmaxf(fmaxf(scv[0], scv[1]), fmaxf(scv[2], scv[3]));
    float wsum = 0.f;
    #pragma unroll
    for (int tt = 0; tt < T_; ++tt) { scv[tt] = expf(scv[tt] - mx); wsum += scv[tt]; }
    float winv = 1.f / wsum;

    float hf[D_];
    #pragma unroll
    for (int j = 0; j < D_; ++j) hf[j] = 0.f;
    #pragma unroll
    for (int tt = 0; tt < T_; ++tt) {
        float w = scv[tt] * winv;
        const float4* kr = (const float4*)(kp + tt*D_);
        #pragma unroll
        for (int c4 = 0; c4 < D_/4; ++c4) {
            float4 v = kr[c4];
            hf[4*c4+0] = fmaf(v.x, w, hf[4*c4+0]);
            hf[4*c4+1] = fmaf(v.y, w, hf[4*c4+1]);
            hf[4*c4+2] = fmaf(v.z, w, hf[4*c4+2]);
            hf[4*c4+3] = fmaf(v.w, w, hf[4*c4+3]);
        }
    }
    float ol0 = slb2[0], ol1 = slb2[1], ol2 = slb2[2], ol3 = slb2[3];
    #pragma unroll 2
    for (int j = 0; j < 32; ++j) {
        float a = slb1[j];
        const float4* wr = (const float4*)(&sl1[j*D_]);
        #pragma unroll
        for (int c4 = 0; c4 < D_/4; ++c4) {
            float4 v = wr[c4];
            a = fmaf(hf[4*c4+0], v.x, a);
            a = fmaf(hf[4*c4+1], v.y, a);
            a = fmaf(hf[4*c4+2], v.z, a);
            a = fmaf(hf[4*c4+3], v.w, a);
        }
        a = fmaxf(a, 0.f);
        ol0 = fmaf(a, sl2[0*32+j], ol0);
        ol1 = fmaf(a, sl2[1*32+j], ol1);
        ol2 = fmaf(a, sl2[2*32+j], ol2);
        ol3 = fmaf(a, sl2[3*32+j], ol3);
    }
    float or0 = srb2[0], or1 = srb2[1], or2 = srb2[2], or3 = srb2[3];
    #pragma unroll 2
    for (int j = 0; j < 32; ++j) {
        float a = srb1[j];
        const float4* wr = (const float4*)(&sr1[j*D_]);
        #pragma unroll
        for (int c4 = 0; c4 < D_/4; ++c4) {
            float4 v = wr[c4];
            a = fmaf(hf[4*c4+0], v.x, a);
            a = fmaf(hf[4*c4+1], v.y, a);
            a = fmaf(hf[4*c4+2], v.z, a);
            a = fmaf(hf[4*c4+3], v.w, a);
        }
        a = fmaxf(a, 0.f);
        or0 = fmaf(a, sr2[0*32+j], or0);
        or1 = fmaf(a, sr2[1*32+j], or1);
        or2 = fmaf(a, sr2[2*32+j], or2);
        or3 = fmaf(a, sr2[3*32+j], or3);
    }
    const int NB = B_ * N_;
    out[0*2*NB + rn*2 + 0] = ol0;
    out[0*2*NB + rn*2 + 1] = ol1;
    out[1*2*NB + rn*2 + 0] = softplus_f(ol2) + 1e-6f;
    out[1*2*NB + rn*2 + 1] = softplus_f(ol3) + 1e-6f;
    out[2*2*NB + rn*2 + 0] = or0;
    out[2*2*NB + rn*2 + 1] = or1;
    out[3*2*NB + rn*2 + 0] = softplus_f(or2) + 1e-6f;
    out[3*2*NB + rn*2 + 1] = softplus_f(or3) + 1e-6f;
}

// ---- launcher ----
extern "C" void kernel_launch(void* const* d_in, const int* in_sizes, int n_in,
                              void* d_out, int out_size, void* d_ws, size_t ws_size,
                              hipStream_t stream)
{
    const float* x   = (const float*)d_in[0];
    const float* ew1 = (const float*)d_in[1];
    const float* eb1 = (const float*)d_in[2];
    const float* g1  = (const float*)d_in[3];
    const float* bb1 = (const float*)d_in[4];
    const float* m1  = (const float*)d_in[5];
    const float* v1  = (const float*)d_in[6];
    const float* ew2 = (const float*)d_in[7];
    const float* eb2 = (const float*)d_in[8];
    const float* g2  = (const float*)d_in[9];
    const float* bb2 = (const float*)d_in[10];
    const float* m2  = (const float*)d_in[11];
    const float* v2  = (const float*)d_in[12];
    const float* gw  = (const float*)d_in[13];
    const float* att = (const float*)d_in[14];
    const float* qw  = (const float*)d_in[15];
    const float* qb  = (const float*)d_in[16];
    const float* kw  = (const float*)d_in[17];
    const float* kb  = (const float*)d_in[18];
    const float* lw1 = (const float*)d_in[19];
    const float* lb1 = (const float*)d_in[20];
    const float* lw2 = (const float*)d_in[21];
    const float* lb2 = (const float*)d_in[22];
    const float* rw1 = (const float*)d_in[23];
    const float* rb1 = (const float*)d_in[24];
    const float* rw2 = (const float*)d_in[25];
    const float* rb2 = (const float*)d_in[26];
    float* out = (float*)d_out;

    const size_t NTOT = (size_t)BT_*N_;                 // 65536
    float* h    = (float*)d_ws;                         // NTOT*64
    float* hw   = h   + NTOT*D_;                        // NTOT*64
    float* kvb  = hw  + NTOT*D_;                        // NTOT*64
    float* ssf  = kvb + NTOT*D_;                        // NTOT*4
    float* snbf = ssf + NTOT*H_;                        // NTOT*4
    int*   idx  = (int*)(snbf + NTOT*H_);               // NTOT*16
    float* q    = (float*)(idx + NTOT*K_);              // B*N*64
    float2* sp2g = (float2*)(q + (size_t)B_*N_*D_);     // NTOT float2
    int*   sidg = (int*)((float*)sp2g + 2*NTOT);        // NTOT
    int*   fail_cnt = sidg + NTOT;                      // 32
    int*   fail_lst = fail_cnt + 32;                    // NTOT

    k_root<<<BT_ + BT_*N_/256, 1024, 0, stream>>>(x, ew1, eb1, g1, bb1, m1, v1,
                                                  ew2, eb2, g2, bb2, m2, v2,
                                                  h, sp2g, sidg, fail_cnt);
    k_gatw_b1<<<BT_*N_/64 + BT_*(N_/64), 256, 0, stream>>>(
        h, gw, att, hw, ssf, snbf, sp2g, sidg, idx, fail_cnt, fail_lst);
    k_knn_b2<<<BT_*128, 256, 0, stream>>>(sp2g, sidg, fail_cnt, fail_lst, idx);
    k_gat<<<(BT_*N_*H_)/256, 256, 0, stream>>>(hw, ssf, snbf, idx, h);
    k_qkv<<<(BT_*N_ + B_*N_)/64, 256, 0, stream>>>(h, qw, qb, kw, kb, q, kvb);
    k_head<<<(B_*N_)/64, 64, 0, stream>>>(q, kvb, lw1, lb1, lw2, lb2,
                                          rw1, rb1, rw2, rb2, out);
}

// Round 17
// 210.128 us; speedup vs baseline: 1.0180x; 1.0172x over previous
//
#include <hip/hip_runtime.h>
#include <math.h>

#define B_ 8
#define T_ 4
#define N_ 2048
#define C_ 11
#define D_ 64
#define H_ 4
#define HD_ 16
#define K_ 16
#define BT_ (B_*T_)

__device__ __forceinline__ float softplus_f(float x) {
    return fmaxf(x, 0.f) + log1pf(expf(-fabsf(x)));
}

// ---- Kernel A: block-specialized  [sort (blocks 0..31)] ∥ [embed MLP] -----
// Sort branch: per-bt bitonic sort by (x,idx) key, zero fail counters.
// Embed branch: BN-folded 2-layer MLP, 4 threads/row, XOR-swizzled sw2.
__global__ __launch_bounds__(1024) void k_root(
    const float* __restrict__ x,
    const float* __restrict__ w1, const float* __restrict__ b1,
    const float* __restrict__ g1, const float* __restrict__ bb1,
    const float* __restrict__ m1, const float* __restrict__ v1,
    const float* __restrict__ w2, const float* __restrict__ b2,
    const float* __restrict__ g2, const float* __restrict__ bb2,
    const float* __restrict__ m2, const float* __restrict__ v2,
    float* __restrict__ h,
    float2* __restrict__ sp2g, int* __restrict__ sidg, int* __restrict__ fail_cnt)
{
    __shared__ unsigned long long smemU[3072];   // 24 KB, branch-carved
    int t = threadIdx.x;

    if (blockIdx.x < BT_) {
        // ================= sort branch =================
        unsigned long long* kvs = smemU;                 // 2048 ull
        float* lyy = (float*)(smemU + 2048);             // 2048 f
        int bt = blockIdx.x;
        if (t == 0) fail_cnt[bt] = 0;
        const float* xb = x + (size_t)bt * N_ * C_;
        for (int m = t; m < N_; m += 1024) {
            float a = xb[m*C_], b = xb[m*C_+1];
            unsigned int bits = __float_as_uint(a);
            unsigned int u = (bits & 0x80000000u) ? ~bits : (bits | 0x80000000u);
            kvs[m] = ((unsigned long long)u << 11) | (unsigned)m;
            lyy[m] = b;
        }
        __syncthreads();
        for (int k = 2; k <= N_; k <<= 1) {
            for (int j = k >> 1; j > 0; j >>= 1) {
                int p = t;
                int i = ((p & ~(j-1)) << 1) | (p & (j-1));
                int l = i | j;
                unsigned long long a = kvs[i], b = kvs[l];
                bool asc = (i & k) == 0;
                if ((a > b) == asc) { kvs[i] = b; kvs[l] = a; }
                __syncthreads();
            }
        }
        float2* op = sp2g + (size_t)bt * N_;
        int*    oi = sidg + (size_t)bt * N_;
        for (int m = t; m < N_; m += 1024) {
            unsigned long long key = kvs[m];
            int id = (int)(key & 0x7FFull);
            unsigned int u = (unsigned int)(key >> 11);
            unsigned int bits = (u & 0x80000000u) ? (u & 0x7FFFFFFFu) : ~u;
            op[m] = make_float2(__uint_as_float(bits), lyy[id]);
            oi[m] = id;
        }
    } else {
        // ================= embed branch =================
        float* fs  = (float*)smemU;
        float* sw1 = fs;            // 352
        float* sb1 = fs + 352;      // 32
        float* sw2 = fs + 384;      // 2048
        float* sb2 = fs + 2432;     // 64
        if (t < 32) {
            float s = g1[t] / sqrtf(v1[t] + 1e-5f);
            sb1[t] = (b1[t] - m1[t]) * s + bb1[t];
            for (int c = 0; c < C_; ++c) sw1[t*C_+c] = w1[t*C_+c] * s;
        } else if (t >= 64 && t < 128) {
            int j = t - 64;
            float s = g2[j] / sqrtf(v2[j] + 1e-5f);
            sb2[j] = (b2[j] - m2[j]) * s + bb2[j];
            int key = (j >> 4) & 3;
            for (int c = 0; c < 32; ++c)
                sw2[j*32 + ((((c>>2) ^ key) << 2) | (c & 3))] = w2[j*32+c] * s;
        }
        __syncthreads();

        int node = (blockIdx.x - BT_) * 256 + (t >> 2);
        int g = t & 3;
        const float* xp = x + (size_t)node * C_;
        float xin[C_];
        #pragma unroll
        for (int c = 0; c < C_; ++c) xin[c] = xp[c];

        float t1[32];
        #pragma unroll
        for (int j = 0; j < 32; ++j) {
            float a = sb1[j];
            #pragma unroll
            for (int c = 0; c < C_; ++c) a = fmaf(xin[c], sw1[j*C_+c], a);
            t1[j] = fmaxf(a, 0.f);
        }
        float4* hp4 = (float4*)(h + (size_t)node * D_ + g * 16);
        #pragma unroll
        for (int j4 = 0; j4 < 4; ++j4) {
            float o[4];
            #pragma unroll
            for (int u = 0; u < 4; ++u) {
                int j = g*16 + j4*4 + u;
                float a = sb2[j];
                #pragma unroll
                for (int c4 = 0; c4 < 8; ++c4) {
                    float4 w4 = *(const float4*)(&sw2[j*32 + ((c4 ^ g) << 2)]);
                    a = fmaf(t1[4*c4+0], w4.x, a);
                    a = fmaf(t1[4*c4+1], w4.y, a);
                    a = fmaf(t1[4*c4+2], w4.z, a);
                    a = fmaf(t1[4*c4+3], w4.w, a);
                }
                o[u] = fmaxf(a, 0.f);
            }
            hp4[j4] = make_float4(o[0], o[1], o[2], o[3]);
        }
    }
}

// ---- Kernel B: block-specialized [gatw (blocks 0..1023)] ∥ [knn_b1] -------
__global__ __launch_bounds__(256) void k_gatw_b1(
    const float* __restrict__ h, const float* __restrict__ gw,
    const float* __restrict__ att,
    float* __restrict__ hw, float* __restrict__ ssf, float* __restrict__ snbf,
    const float2* __restrict__ sp2g, const int* __restrict__ sidg,
    int* __restrict__ idx, int* __restrict__ fail_cnt, int* __restrict__ fail_lst)
{
    __shared__ float4 smemQ[1088];   // 17408 B, branch-carved
    int t = threadIdx.x;

    if (blockIdx.x < BT_*N_/64) {
        // ================= gatw branch =================
        float* sw   = (float*)smemQ;     // 4096
        float* satA = sw + 4096;         // 128
        for (int i = t; i < D_*D_; i += 256) {
            int r = i >> 6, c = i & 63;
            sw[r*64 + ((((c>>2) ^ ((r>>4)&3)) << 2) | (c & 3))] = gw[i];
        }
        if (t < 2*H_*HD_) satA[t] = att[t];
        __syncthreads();

        int node = blockIdx.x * 64 + (t >> 2);
        int hh = t & 3;
        const float* hp = h + (size_t)node * D_;
        float hin[D_];
        #pragma unroll
        for (int j = 0; j < D_; j += 4) {
            float4 v = *(const float4*)(hp + j);
            hin[j] = v.x; hin[j+1] = v.y; hin[j+2] = v.z; hin[j+3] = v.w;
        }
        float4* wp4 = (float4*)(hw + (size_t)node * D_ + hh * HD_);
        float ss = 0.f, sn = 0.f;
        #pragma unroll
        for (int q4 = 0; q4 < 4; ++q4) {
            float o[4];
            #pragma unroll
            for (int u = 0; u < 4; ++u) {
                const int jj = q4*4 + u;
                const int j = hh*HD_ + jj;
                float a = 0.f;
                #pragma unroll
                for (int c4 = 0; c4 < D_/4; ++c4) {
                    float4 w4 = *(const float4*)(&sw[j*64 + ((c4 ^ hh) << 2)]);
                    a = fmaf(hin[4*c4+0], w4.x, a);
                    a = fmaf(hin[4*c4+1], w4.y, a);
                    a = fmaf(hin[4*c4+2], w4.z, a);
                    a = fmaf(hin[4*c4+3], w4.w, a);
                }
                o[u] = a;
                ss = fmaf(a, satA[hh*(2*HD_) + jj], ss);
                sn = fmaf(a, satA[hh*(2*HD_) + HD_ + jj], sn);
            }
            wp4[q4] = make_float4(o[0], o[1], o[2], o[3]);
        }
        ssf[(size_t)node * H_ + hh] = ss;
        snbf[(size_t)node * H_ + hh] = sn;
        return;
    }

    // ================= knn_b1 branch =================
    float2* spw = (float2*)smemQ;                 // 640 float2
    int* sidw   = (int*)((float*)smemQ + 1280);   // 640
    int* scnt   = sidw + 640;                     // 64
    const int bid   = blockIdx.x - BT_*N_/64;
    const int bt    = bid >> 5;
    const int qbase = (bid & 31) << 6;
    const int base  = qbase - 288;
    const float2* pb = sp2g + (size_t)bt * N_;
    const int*    ib = sidg + (size_t)bt * N_;
    for (int L = t; L < 640; L += 256) {
        int r = base + L;
        if (r < 0 || r >= N_) { spw[L] = make_float2(1e18f, 0.f); sidw[L] = 0; }
        else { spw[L] = pb[r]; sidw[L] = ib[r]; }
    }
    if (t < 64) scnt[t] = 0;
    __syncthreads();

    const int q = t >> 2;
    const int g = t & 3;
    const int s = qbase + q;
    const int sLoc = q + 288;
    const float xs = spw[sLoc].x, ys = spw[sLoc].y;
    const float sqn = __fmaf_rn(xs, xs, __fmul_rn(ys, ys));

    float bd[K_];
    #pragma unroll
    for (int i = 0; i < K_; ++i) bd[i] = 3.402823466e38f;

    for (int i = 0; i < 8; ++i) {
        float d[16];
        #pragma unroll
        for (int j = 0; j < 16; ++j) {
            float2 p = spw[q + 32 + 64*i + 4*j + g];
            float sps = __fmaf_rn(p.x, p.x, __fmul_rn(p.y, p.y));
            float tt = __fmul_rn(xs, p.x);
            tt = __fmaf_rn(ys, p.y, tt);
            d[j] = __fmaf_rn(-2.f, tt, sps);
        }
        #pragma unroll
        for (int k = 2; k <= 16; k <<= 1) {
            #pragma unroll
            for (int jj = k >> 1; jj > 0; jj >>= 1) {
                #pragma unroll
                for (int ii = 0; ii < 16; ++ii) {
                    int ll = ii ^ jj;
                    if (ll > ii) {
                        float lo = fminf(d[ii], d[ll]);
                        float hi = fmaxf(d[ii], d[ll]);
                        if ((ii & k) == 0) { d[ii] = lo; d[ll] = hi; }
                        else               { d[ii] = hi; d[ll] = lo; }
                    }
                }
            }
        }
        #pragma unroll
        for (int ii = 0; ii < 16; ++ii) bd[ii] = fminf(bd[ii], d[15-ii]);
        #pragma unroll
        for (int jj = 8; jj > 0; jj >>= 1) {
            #pragma unroll
            for (int ii = 0; ii < 16; ++ii) {
                int ll = ii ^ jj;
                if (ll > ii) {
                    float lo = fminf(bd[ii], bd[ll]);
                    float hi = fmaxf(bd[ii], bd[ll]);
                    bd[ii] = lo; bd[ll] = hi;
                }
            }
        }
    }

    #pragma unroll
    for (int st = 1; st <= 2; st <<= 1) {
        float pr[K_];
        #pragma unroll
        for (int i = 0; i < K_; ++i) pr[i] = __shfl_xor(bd[K_-1-i], st, 64);
        #pragma unroll
        for (int i = 0; i < K_; ++i) bd[i] = fminf(bd[i], pr[i]);
        #pragma unroll
        for (int dd = 8; dd >= 1; dd >>= 1) {
            #pragma unroll
            for (int i = 0; i < K_; ++i) {
                if ((i & dd) == 0) {
                    float lo = fminf(bd[i], bd[i+dd]);
                    float hi = fmaxf(bd[i], bd[i+dd]);
                    bd[i] = lo; bd[i+dd] = hi;
                }
            }
        }
    }
    const float d15 = bd[K_-1];

    float d15s = d15 + sqn;
    float bound = d15s * 1.0001f + (sqn + 1.0f) * 1e-5f;
    bool leftOK = (s - 257 < 0);
    if (!leftOK) { float gp = xs - spw[q+31].x;  leftOK  = (gp*gp >= bound); }
    bool rightOK = (s + 256 > N_-1);
    if (!rightOK){ float gp = spw[q+544].x - xs; rightOK = (gp*gp >= bound); }
    if (!(leftOK && rightOK) && g == 0) {
        int fp = atomicAdd(&fail_cnt[bt], 1);
        fail_lst[bt*N_ + fp] = s;
    }

    int n = sidw[sLoc];
    int* op = idx + ((size_t)bt * N_ + n) * K_;
    for (int i = 0; i < 16; ++i) {
        float d[8];
        int Lb = q + 32 + 32*i + g;
        #pragma unroll
        for (int j = 0; j < 8; ++j) {
            float2 p = spw[Lb + 4*j];
            float sps = __fmaf_rn(p.x, p.x, __fmul_rn(p.y, p.y));
            float tt = __fmul_rn(xs, p.x);
            tt = __fmaf_rn(ys, p.y, tt);
            d[j] = __fmaf_rn(-2.f, tt, sps);
        }
        float dm0 = fminf(fminf(d[0],d[1]), fminf(d[2],d[3]));
        float dm1 = fminf(fminf(d[4],d[5]), fminf(d[6],d[7]));
        if (fminf(dm0, dm1) <= d15) {
            #pragma unroll
            for (int j = 0; j < 8; ++j) {
                if (d[j] <= d15) {
                    int c = atomicAdd(&scnt[q], 1);
                    if (c < K_) op[c] = sidw[Lb + 4*j];
                }
            }
        }
    }
}

// ---- Kernel B2: chunk-parallel full-scan fallback (early-exit grid) -------
__global__ __launch_bounds__(256) void k_knn_b2(const float2* __restrict__ sp2g,
    const int* __restrict__ sidg, const int* __restrict__ fail_cnt,
    const int* __restrict__ fail_lst, int* __restrict__ idx)
{
    const int bt    = blockIdx.x >> 7;
    const int chunk = blockIdx.x & 127;
    const int nf = fail_cnt[bt];
    if (chunk * 16 >= nf) return;

    __shared__ float2 sp[N_];
    __shared__ int sid[N_];
    __shared__ int scnt[16];
    const float2* pb = sp2g + (size_t)bt * N_;
    const int*    ib = sidg + (size_t)bt * N_;
    for (int m = threadIdx.x; m < N_; m += 256) { sp[m] = pb[m]; sid[m] = ib[m]; }
    if (threadIdx.x < 16) scnt[threadIdx.x] = 0;
    __syncthreads();

    const int q = threadIdx.x >> 4;
    const int g = threadIdx.x & 15;
    const bool active = (chunk*16 + q) < nf;
    const int s = active ? fail_lst[bt*N_ + chunk*16 + q] : 0;
    const float xs = sp[s].x, ys = sp[s].y;

    float bd[K_];
    #pragma unroll
    for (int i = 0; i < K_; ++i) bd[i] = 3.402823466e38f;

    for (int i = 0; i < 8; ++i) {
        float d[16];
        #pragma unroll
        for (int j = 0; j < 16; ++j) {
            float2 p = sp[256*i + 16*j + g];
            float sps = __fmaf_rn(p.x, p.x, __fmul_rn(p.y, p.y));
            float tt = __fmul_rn(xs, p.x);
            tt = __fmaf_rn(ys, p.y, tt);
            d[j] = __fmaf_rn(-2.f, tt, sps);
        }
        #pragma unroll
        for (int k = 2; k <= 16; k <<= 1) {
            #pragma unroll
            for (int jj = k >> 1; jj > 0; jj >>= 1) {
                #pragma unroll
                for (int ii = 0; ii < 16; ++ii) {
                    int ll = ii ^ jj;
                    if (ll > ii) {
                        float lo = fminf(d[ii], d[ll]);
                        float hi = fmaxf(d[ii], d[ll]);
                        if ((ii & k) == 0) { d[ii] = lo; d[ll] = hi; }
                        else               { d[ii] = hi; d[ll] = lo; }
                    }
                }
            }
        }
        #pragma unroll
        for (int ii = 0; ii < 16; ++ii) bd[ii] = fminf(bd[ii], d[15-ii]);
        #pragma unroll
        for (int jj = 8; jj > 0; jj >>= 1) {
            #pragma unroll
            for (int ii = 0; ii < 16; ++ii) {
                int ll = ii ^ jj;
                if (ll > ii) {
                    float lo = fminf(bd[ii], bd[ll]);
                    float hi = fmaxf(bd[ii], bd[ll]);
                    bd[ii] = lo; bd[ll] = hi;
                }
            }
        }
    }

    #pragma unroll
    for (int st = 1; st <= 8; st <<= 1) {
        float pr[K_];
        #pragma unroll
        for (int i = 0; i < K_; ++i) pr[i] = __shfl_xor(bd[K_-1-i], st, 64);
        #pragma unroll
        for (int i = 0; i < K_; ++i) bd[i] = fminf(bd[i], pr[i]);
        #pragma unroll
        for (int dd = 8; dd >= 1; dd >>= 1) {
            #pragma unroll
            for (int i = 0; i < K_; ++i) {
                if ((i & dd) == 0) {
                    float lo = fminf(bd[i], bd[i+dd]);
                    float hi = fmaxf(bd[i], bd[i+dd]);
                    bd[i] = lo; bd[i+dd] = hi;
                }
            }
        }
    }
    const float d15 = bd[K_-1];

    int n = sid[s];
    int* op = idx + ((size_t)bt * N_ + n) * K_;
    for (int i = 0; i < 16; ++i) {
        float d[8];
        #pragma unroll
        for (int j = 0; j < 8; ++j) {
            float2 p = sp[128*i + 16*j + g];
            float sps = __fmaf_rn(p.x, p.x, __fmul_rn(p.y, p.y));
            float tt = __fmul_rn(xs, p.x);
            tt = __fmaf_rn(ys, p.y, tt);
            d[j] = __fmaf_rn(-2.f, tt, sps);
        }
        float dm0 = fminf(fminf(d[0],d[1]), fminf(d[2],d[3]));
        float dm1 = fminf(fminf(d[4],d[5]), fminf(d[6],d[7]));
        if (active && fminf(dm0, dm1) <= d15) {
            #pragma unroll
            for (int j = 0; j < 8; ++j) {
                if (d[j] <= d15) {
                    int c = atomicAdd(&scnt[q], 1);
                    if (c < K_) op[c] = sid[128*i + 16*j + g];
                }
            }
        }
    }
}

// ---- Kernel C2: GAT gather/softmax/aggregate + residual ----
__global__ __launch_bounds__(256, 4) void k_gat(
    const float* __restrict__ hw, const float* __restrict__ ssf,
    const float* __restrict__ snbf,
    const int* __restrict__ idx,
    float* __restrict__ h /* in-out: becomes h_sp */)
{
    const int t = threadIdx.x;
    const int xcd   = blockIdx.x & 7;
    const int local = blockIdx.x >> 3;
    const int btl   = local >> 5;
    const int chunk = local & 31;
    const int bt    = xcd * 4 + btl;
    const int node  = bt * N_ + chunk * 64 + (t >> 2);
    const int hh    = t & 3;

    const int* ip = idx + (size_t)node * K_;
    float ssv = ssf[(size_t)node*H_ + hh];
    const float* hwb = hw + ((size_t)bt * N_) * D_;
    const float* snb = snbf + ((size_t)bt * N_) * H_;

    int nb[K_];
    #pragma unroll
    for (int k = 0; k < K_; ++k) nb[k] = ip[k];

    float sc[K_];
    float mx = -3.402823466e38f;
    #pragma unroll
    for (int k = 0; k < K_; ++k) {
        float s = ssv + snb[(size_t)nb[k]*H_ + hh];
        s = (s >= 0.f) ? s : 0.2f * s;
        sc[k] = s;
        mx = fmaxf(mx, s);
    }
    float den = 0.f;
    #pragma unroll
    for (int k = 0; k < K_; ++k) { sc[k] = __expf(sc[k] - mx); den += sc[k]; }
    float inv = 1.f / den;

    float acc[HD_];
    #pragma unroll
    for (int i = 0; i < HD_; ++i) acc[i] = 0.f;
    #pragma unroll
    for (int k = 0; k < K_; ++k) {
        float al = sc[k] * inv;
        const float* vp = hwb + (size_t)nb[k]*D_ + hh*HD_;
        #pragma unroll
        for (int i = 0; i < HD_; i += 4) {
            float4 v = *(const float4*)(vp + i);
            acc[i]   = fmaf(v.x, al, acc[i]);
            acc[i+1] = fmaf(v.y, al, acc[i+1]);
            acc[i+2] = fmaf(v.z, al, acc[i+2]);
            acc[i+3] = fmaf(v.w, al, acc[i+3]);
        }
    }
    float4* hp4 = (float4*)(h + (size_t)node*D_ + hh*HD_);
    #pragma unroll
    for (int i4 = 0; i4 < 4; ++i4) {
        float4 old = hp4[i4];
        hp4[i4] = make_float4(fmaxf(acc[4*i4+0] + old.x, 0.f),
                              fmaxf(acc[4*i4+1] + old.y, 0.f),
                              fmaxf(acc[4*i4+2] + old.z, 0.f),
                              fmaxf(acc[4*i4+3] + old.w, 0.f));
    }
}

// ---- Kernel D1: Q and KV projections; 4 thr/row; XOR-swizzled weights -----
__global__ __launch_bounds__(256) void k_qkv(
    const float* __restrict__ hsp,
    const float* __restrict__ qw, const float* __restrict__ qb,
    const float* __restrict__ kw, const float* __restrict__ kb,
    float* __restrict__ q, float* __restrict__ kv)
{
    __shared__ float s_qw[D_*D_], s_kw[D_*D_], s_qb[D_], s_kb[D_];
    int t = threadIdx.x;
    for (int i = t; i < D_*D_; i += 256) {
        int r = i >> 6, c = i & 63;
        int p = r*64 + ((((c>>2) ^ ((r>>4)&3)) << 2) | (c & 3));
        s_qw[p] = qw[i]; s_kw[p] = kw[i];
    }
    if (t < D_) { s_qb[t] = qb[t]; s_kb[t] = kb[t]; }
    __syncthreads();

    int r = blockIdx.x * 64 + (t >> 2);
    int g = t & 3;
    const float* in; float* outp; const float* W; const float* bb;
    if (r < BT_*N_) {
        int bt = r >> 11; int n = r & (N_-1);
        int b = bt >> 2, tt = bt & 3;
        in = hsp + (size_t)r * D_;
        outp = kv + (((size_t)(b*N_ + n))*T_ + tt) * D_;
        W = s_kw; bb = s_kb;
    } else {
        int rr = r - BT_*N_;
        int b = rr >> 11, n = rr & (N_-1);
        in = hsp + ((size_t)(b*T_ + (T_-1))*N_ + n) * D_;
        outp = q + (size_t)rr * D_;
        W = s_qw; bb = s_qb;
    }
    float xin[D_];
    #pragma unroll
    for (int j = 0; j < D_; j += 4) {
        float4 v = *(const float4*)(in + j);
        xin[j] = v.x; xin[j+1] = v.y; xin[j+2] = v.z; xin[j+3] = v.w;
    }
    float4* outp4 = (float4*)(outp + g * 16);
    #pragma unroll
    for (int j4 = 0; j4 < 4; ++j4) {
        float o[4];
        #pragma unroll
        for (int u = 0; u < 4; ++u) {
            int j = g*16 + j4*4 + u;
            float a = bb[j];
            #pragma unroll
            for (int c4 = 0; c4 < D_/4; ++c4) {
                float4 w4 = *(const float4*)(&W[j*64 + ((c4 ^ g) << 2)]);
                a = fmaf(xin[4*c4+0], w4.x, a);
                a = fmaf(xin[4*c4+1], w4.y, a);
                a = fmaf(xin[4*c4+2], w4.z, a);
                a = fmaf(xin[4*c4+3], w4.w, a);
            }
            o[u] = a;
        }
        outp4[j4] = make_float4(o[0], o[1], o[2], o[3]);
    }
}

// ---- Kernel D2: temporal attention + output heads ----
__global__ __launch_bounds__(64) void k_head(
    const float* __restrict__ q, const float* __restrict__ kv,
    const float* __restrict__ lw1, const float* __restrict__ lb1,
    const float* __restrict__ lw2, const float* __restrict__ lb2,
    const float* __restrict__ rw1, const float* __restrict__ rb1,
    const float* __restrict__ rw2, const float* __restrict__ rb2,
    float* __restrict__ out)
{
    __shared__ float sl1[32*D_], sr1[32*D_], sl2[4*32], sr2[4*32];
    __shared__ float slb1[32], srb1[32], slb2[4], srb2[4];
    int t = threadIdx.x;
    for (int i = t; i < 32*D_; i += 64) { sl1[i] = lw1[i]; sr1[i] = rw1[i]; }
    for (int i = t; i < 128; i += 64)   { sl2[i] = lw2[i]; sr2[i] = rw2[i]; }
    if (t < 32) { slb1[t] = lb1[t]; srb1[t] = rb1[t]; }
    if (t < 4)  { slb2[t] = lb2[t]; srb2[t] = rb2[t]; }
    __syncthreads();

    int rn = blockIdx.x * 64 + t;
    const float* qp = q + (size_t)rn * D_;
    const float* kp = kv + (size_t)rn * T_ * D_;

    float qv[D_];
    #pragma unroll
    for (int j = 0; j < D_; j += 4) {
        float4 v = *(const float4*)(qp + j);
        qv[j] = v.x; qv[j+1] = v.y; qv[j+2] = v.z; qv[j+3] = v.w;
    }
    float scv[T_];
    #pragma unroll
    for (int tt = 0; tt < T_; ++tt) {
        float a = 0.f;
        const float4* kr = (const float4*)(kp + tt*D_);
        #pragma unroll
        for (int c4 = 0; c4 < D_/4; ++c4) {
            float4 v = kr[c4];
            a = fmaf(qv[4*c4+0], v.x, a);
            a = fmaf(qv[4*c4+1], v.y, a);
            a = fmaf(qv[4*c4+2], v.z, a);
            a = fmaf(qv[4*c4+3], v.w, a);
        }
        scv[tt] = a * 0.125f;
    }
    float mx = fmaxf(fmaxf(scv[0], scv[1]), fmaxf(scv[2], scv[3]));
    float wsum = 0.f;
    #pragma unroll
    for (int tt = 0; tt < T_; ++tt) { scv[tt] = expf(scv[tt] - mx); wsum += scv[tt]; }
    float winv = 1.f / wsum;

    float hf[D_];
    #pragma unroll
    for (int j = 0; j < D_; ++j) hf[j] = 0.f;
    #pragma unroll
    for (int tt = 0; tt < T_; ++tt) {
        float w = scv[tt] * winv;
        const float4* kr = (const float4*)(kp + tt*D_);
        #pragma unroll
        for (int c4 = 0; c4 < D_/4; ++c4) {
            float4 v = kr[c4];
            hf[4*c4+0] = fmaf(v.x, w, hf[4*c4+0]);
            hf[4*c4+1] = fmaf(v.y, w, hf[4*c4+1]);
            hf[4*c4+2] = fmaf(v.z, w, hf[4*c4+2]);
            hf[4*c4+3] = fmaf(v.w, w, hf[4*c4+3]);
        }
    }
    float ol0 = slb2[0], ol1 = slb2[1], ol2 = slb2[2], ol3 = slb2[3];
    #pragma unroll 2
    for (int j = 0; j < 32; ++j) {
        float a = slb1[j];
        const float4* wr = (const float4*)(&sl1[j*D_]);
        #pragma unroll
        for (int c4 = 0; c4 < D_/4; ++c4) {
            float4 v = wr[c4];
            a = fmaf(hf[4*c4+0], v.x, a);
            a = fmaf(hf[4*c4+1], v.y, a);
            a = fmaf(hf[4*c4+2], v.z, a);
            a = fmaf(hf[4*c4+3], v.w, a);
        }
        a = fmaxf(a, 0.f);
        ol0 = fmaf(a, sl2[0*32+j], ol0);
        ol1 = fmaf(a, sl2[1*32+j], ol1);
        ol2 = fmaf(a, sl2[2*32+j], ol2);
        ol3 = fmaf(a, sl2[3*32+j], ol3);
    }
    float or0 = srb2[0], or1 = srb2[1], or2 = srb2[2], or3 = srb2[3];
    #pragma unroll 2
    for (int j = 0; j < 32; ++j) {
        float a = srb1[j];
        const float4* wr = (const float4*)(&sr1[j*D_]);
        #pragma unroll
        for (int c4 = 0; c4 < D_/4; ++c4) {
            float4 v = wr[c4];
            a = fmaf(hf[4*c4+0], v.x, a);
            a = fmaf(hf[4*c4+1], v.y, a);
            a = fmaf(hf[4*c4+2], v.z, a);
            a = fmaf(hf[4*c4+3], v.w, a);
        }
        a = fmaxf(a, 0.f);
        or0 = fmaf(a, sr2[0*32+j], or0);
        or1 = fmaf(a, sr2[1*32+j], or1);
        or2 = fmaf(a, sr2[2*32+j], or2);
        or3 = fmaf(a, sr2[3*32+j], or3);
    }
    const int NB = B_ * N_;
    out[0*2*NB + rn*2 + 0] = ol0;
    out[0*2*NB + rn*2 + 1] = ol1;
    out[1*2*NB + rn*2 + 0] = softplus_f(ol2) + 1e-6f;
    out[1*2*NB + rn*2 + 1] = softplus_f(ol3) + 1e-6f;
    out[2*2*NB + rn*2 + 0] = or0;
    out[2*2*NB + rn*2 + 1] = or1;
    out[3*2*NB + rn*2 + 0] = softplus_f(or2) + 1e-6f;
    out[3*2*NB + rn*2 + 1] = softplus_f(or3) + 1e-6f;
}

// ---- launcher ----
extern "C" void kernel_launch(void* const* d_in, const int* in_sizes, int n_in,
                              void* d_out, int out_size, void* d_ws, size_t ws_size,
                              hipStream_t stream)
{
    const float* x   = (const float*)d_in[0];
    const float* ew1 = (const float*)d_in[1];
    const float* eb1 = (const float*)d_in[2];
    const float* g1  = (const float*)d_in[3];
    const float* bb1 = (const float*)d_in[4];
    const float* m1  = (const float*)d_in[5];
    const float* v1  = (const float*)d_in[6];
    const float* ew2 = (const float*)d_in[7];
    const float* eb2 = (const float*)d_in[8];
    const float* g2  = (const float*)d_in[9];
    const float* bb2 = (const float*)d_in[10];
    const float* m2  = (const float*)d_in[11];
    const float* v2  = (const float*)d_in[12];
    const float* gw  = (const float*)d_in[13];
    const float* att = (const float*)d_in[14];
    const float* qw  = (const float*)d_in[15];
    const float* qb  = (const float*)d_in[16];
    const float* kw  = (const float*)d_in[17];
    const float* kb  = (const float*)d_in[18];
    const float* lw1 = (const float*)d_in[19];
    const float* lb1 = (const float*)d_in[20];
    const float* lw2 = (const float*)d_in[21];
    const float* lb2 = (const float*)d_in[22];
    const float* rw1 = (const float*)d_in[23];
    const float* rb1 = (const float*)d_in[24];
    const float* rw2 = (const float*)d_in[25];
    const float* rb2 = (const float*)d_in[26];
    float* out = (float*)d_out;

    const size_t NTOT = (size_t)BT_*N_;                 // 65536
    float* h    = (float*)d_ws;                         // NTOT*64
    float* hw   = h   + NTOT*D_;                        // NTOT*64
    float* kvb  = hw  + NTOT*D_;                        // NTOT*64
    float* ssf  = kvb + NTOT*D_;                        // NTOT*4
    float* snbf = ssf + NTOT*H_;                        // NTOT*4
    int*   idx  = (int*)(snbf + NTOT*H_);               // NTOT*16
    float* q    = (float*)(idx + NTOT*K_);              // B*N*64
    float2* sp2g = (float2*)(q + (size_t)B_*N_*D_);     // NTOT float2
    int*   sidg = (int*)((float*)sp2g + 2*NTOT);        // NTOT
    int*   fail_cnt = sidg + NTOT;                      // 32
    int*   fail_lst = fail_cnt + 32;                    // NTOT

    k_root<<<BT_ + BT_*N_/256, 1024, 0, stream>>>(x, ew1, eb1, g1, bb1, m1, v1,
                                                  ew2, eb2, g2, bb2, m2, v2,
                                                  h, sp2g, sidg, fail_cnt);
    k_gatw_b1<<<BT_*N_/64 + BT_*(N_/64), 256, 0, stream>>>(
        h, gw, att, hw, ssf, snbf, sp2g, sidg, idx, fail_cnt, fail_lst);
    k_knn_b2<<<BT_*128, 256, 0, stream>>>(sp2g, sidg, fail_cnt, fail_lst, idx);
    k_gat<<<(BT_*N_*H_)/256, 256, 0, stream>>>(hw, ssf, snbf, idx, h);
    k_qkv<<<(BT_*N_ + B_*N_)/64, 256, 0, stream>>>(h, qw, qb, kw, kb, q, kvb);
    k_head<<<(B_*N_)/64, 64, 0, stream>>>(q, kvb, lw1, lb1, lw2, lb2,
                                          rw1, rb1, rw2, rb2, out);
}